// Round 1
// baseline (11998.919 us; speedup 1.0000x reference)
//
#include <hip/hip_runtime.h>
#include <cstddef>

#define EPSV 1e-5f

__device__ __forceinline__ float gelu_f(float x) {
    return 0.5f * x * (1.0f + erff(x * 0.7071067811865476f));
}

// ---------------- conv1: 5x5 stride2 pad2, CI=1, CO=32, 128->64 ----------------
__global__ __launch_bounds__(256) void conv1_kernel(
    const float* __restrict__ in, const float* __restrict__ w,
    const float* __restrict__ g, const float* __restrict__ bt,
    const float* __restrict__ mn, const float* __restrict__ vr,
    float* __restrict__ out, int N)
{
    int idx = blockIdx.x * 256 + threadIdx.x;
    if (idx >= N * 32 * 64 * 64) return;
    int ox = idx & 63, oy = (idx >> 6) & 63, co = (idx >> 12) & 31, n = idx >> 17;
    const float* ip = in + (size_t)n * 16384;
    const float* wp = w + co * 25;
    int iy0 = oy * 2 - 2, ix0 = ox * 2 - 2;
    float acc = 0.f;
    #pragma unroll
    for (int ky = 0; ky < 5; ky++) {
        int iy = iy0 + ky;
        if ((unsigned)iy >= 128u) continue;
        #pragma unroll
        for (int kx = 0; kx < 5; kx++) {
            int ix = ix0 + kx;
            if ((unsigned)ix >= 128u) continue;
            acc += wp[ky * 5 + kx] * ip[iy * 128 + ix];
        }
    }
    float inv = g[co] * rsqrtf(vr[co] + EPSV);
    acc = acc * inv + (bt[co] - mn[co] * inv);
    out[idx] = gelu_f(acc);
}

// ---------------- conv 3x3 stride2 pad1 generic (templated CI, HI) ----------------
template<int CI, int HI>
__global__ __launch_bounds__(256) void conv3x3s2_kernel(
    const float* __restrict__ in, const float* __restrict__ w,
    const float* __restrict__ g, const float* __restrict__ bt,
    const float* __restrict__ mn, const float* __restrict__ vr,
    float* __restrict__ out, int N, int CO)
{
    constexpr int HO = HI / 2;
    int idx = blockIdx.x * 256 + threadIdx.x;
    if (idx >= N * CO * HO * HO) return;
    int ox = idx % HO; int t = idx / HO;
    int oy = t % HO; t /= HO;
    int co = t % CO; int n = t / CO;
    const float* wp = w + (size_t)co * (CI * 9);
    const float* ip = in + (size_t)n * (CI * HI * HI);
    int iy0 = oy * 2 - 1, ix0 = ox * 2 - 1;
    float acc = 0.f;
    for (int ci = 0; ci < CI; ci++) {
        const float* ipc = ip + ci * HI * HI;
        const float* wpc = wp + ci * 9;
        #pragma unroll
        for (int ky = 0; ky < 3; ky++) {
            int iy = iy0 + ky;
            if ((unsigned)iy >= (unsigned)HI) continue;
            #pragma unroll
            for (int kx = 0; kx < 3; kx++) {
                int ix = ix0 + kx;
                if ((unsigned)ix >= (unsigned)HI) continue;
                acc += wpc[ky * 3 + kx] * ipc[iy * HI + ix];
            }
        }
    }
    float inv = g[co] * rsqrtf(vr[co] + EPSV);
    acc = acc * inv + (bt[co] - mn[co] * inv);
    out[idx] = gelu_f(acc);
}

// ---------------- 4x4 avg-pool (16x16 -> 4x4) + transpose to (n, p, c) ----------------
__global__ __launch_bounds__(256) void pool_kernel(
    const float* __restrict__ in, float* __restrict__ out, int N)
{
    int idx = blockIdx.x * 256 + threadIdx.x;
    if (idx >= N * 16 * 128) return;
    int c = idx & 127; int p = (idx >> 7) & 15; int n = idx >> 11;
    int ph = p >> 2, pw = p & 3;
    const float* ip = in + (((size_t)n * 128 + c) * 16 + ph * 4) * 16 + pw * 4;
    float s = 0.f;
    #pragma unroll
    for (int dy = 0; dy < 4; dy++)
        #pragma unroll
        for (int dx = 0; dx < 4; dx++)
            s += ip[dy * 16 + dx];
    out[idx] = s * 0.0625f;
}

// ---------------- generic NT SGEMM: C = [res +] act(A[M,K] @ B[N,K]^T + bias) ----------------
// act: 0=none, 1=gelu.  N%64==0, K%16==0 assumed; M guarded.
#define GBM 64
#define GBN 64
#define GBK 16
__global__ __launch_bounds__(256) void gemm_nt_kernel(
    const float* __restrict__ A, const float* __restrict__ B,
    const float* __restrict__ bias, const float* __restrict__ res,
    float* __restrict__ C, int M, int N, int K, int act)
{
    __shared__ __align__(16) float As[GBK][GBM + 4];
    __shared__ __align__(16) float Bs[GBK][GBN + 4];
    int tid = threadIdx.x;
    int bm = blockIdx.y * GBM;
    int bn = blockIdx.x * GBN;
    int tx = tid & 15, ty = tid >> 4;
    int lr = tid >> 2;          // 0..63: tile row for loads
    int lk = (tid & 3) * 4;     // 0,4,8,12: k-offset for float4 load
    float acc[4][4] = {};
    for (int k0 = 0; k0 < K; k0 += GBK) {
        {
            int row = bm + lr;
            float4 av = make_float4(0.f, 0.f, 0.f, 0.f);
            if (row < M) av = *reinterpret_cast<const float4*>(A + (size_t)row * K + k0 + lk);
            As[lk + 0][lr] = av.x; As[lk + 1][lr] = av.y;
            As[lk + 2][lr] = av.z; As[lk + 3][lr] = av.w;
        }
        {
            int row = bn + lr;
            float4 bv = make_float4(0.f, 0.f, 0.f, 0.f);
            if (row < N) bv = *reinterpret_cast<const float4*>(B + (size_t)row * K + k0 + lk);
            Bs[lk + 0][lr] = bv.x; Bs[lk + 1][lr] = bv.y;
            Bs[lk + 2][lr] = bv.z; Bs[lk + 3][lr] = bv.w;
        }
        __syncthreads();
        #pragma unroll
        for (int k = 0; k < GBK; k++) {
            float4 av = *reinterpret_cast<const float4*>(&As[k][ty * 4]);
            float4 bv = *reinterpret_cast<const float4*>(&Bs[k][tx * 4]);
            acc[0][0] += av.x * bv.x; acc[0][1] += av.x * bv.y; acc[0][2] += av.x * bv.z; acc[0][3] += av.x * bv.w;
            acc[1][0] += av.y * bv.x; acc[1][1] += av.y * bv.y; acc[1][2] += av.y * bv.z; acc[1][3] += av.y * bv.w;
            acc[2][0] += av.z * bv.x; acc[2][1] += av.z * bv.y; acc[2][2] += av.z * bv.z; acc[2][3] += av.z * bv.w;
            acc[3][0] += av.w * bv.x; acc[3][1] += av.w * bv.y; acc[3][2] += av.w * bv.z; acc[3][3] += av.w * bv.w;
        }
        __syncthreads();
    }
    #pragma unroll
    for (int i = 0; i < 4; i++) {
        int row = bm + ty * 4 + i;
        if (row >= M) continue;
        #pragma unroll
        for (int j = 0; j < 4; j++) {
            int col = bn + tx * 4 + j;
            if (col >= N) continue;
            float v = acc[i][j];
            if (bias) v += bias[col];
            if (act == 1) v = gelu_f(v);
            if (res) v += res[(size_t)row * N + col];
            C[(size_t)row * N + col] = v;
        }
    }
}

// ---------------- tokens (b,t,p,d) -> tc (b*16+p, t, d) ----------------
__global__ __launch_bounds__(256) void tok2tc_kernel(
    const float* __restrict__ in, float* __restrict__ out)
{
    int idx = blockIdx.x * 256 + threadIdx.x;
    if (idx >= 8 * 32 * 16 * 384) return;
    int d = idx % 384; int t2 = idx / 384;
    int p = t2 & 15; t2 >>= 4;
    int t = t2 & 31; int b = t2 >> 5;
    out[(((size_t)(b * 16 + p) * 32 + t) * 384) + d] = in[idx];
}

// ---------------- depthwise temporal conv (k=3, dilation dil) + bias + gelu ----------------
__global__ __launch_bounds__(256) void dwconv_kernel(
    const float* __restrict__ in, const float* __restrict__ w,
    const float* __restrict__ bias, float* __restrict__ out, int dil)
{
    int idx = blockIdx.x * 256 + threadIdx.x;
    if (idx >= 128 * 32 * 384) return;
    int d = idx % 384; int t = (idx / 384) & 31; int s = idx / (384 * 32);
    const float* ip = in + (size_t)s * 32 * 384 + d;
    float acc = bias[d];
    #pragma unroll
    for (int k = 0; k < 3; k++) {
        int tt = t + (k - 1) * dil;
        if ((unsigned)tt < 32u) acc += w[d * 3 + k] * ip[tt * 384];
    }
    out[idx] = gelu_f(acc);
}

// ---------------- generic LayerNorm over last dim 384 (optional in2 added) ----------------
__global__ __launch_bounds__(128) void ln_kernel(
    const float* __restrict__ in, const float* __restrict__ in2,
    const float* __restrict__ g, const float* __restrict__ b,
    float* __restrict__ out, int rows)
{
    int row = blockIdx.x;
    if (row >= rows) return;
    int t = threadIdx.x;
    const float* ip = in + (size_t)row * 384;
    const float* ip2 = in2 ? in2 + (size_t)row * 384 : nullptr;
    __shared__ float red[128], red2[128];
    float x[3]; float s = 0.f, s2 = 0.f;
    #pragma unroll
    for (int j = 0; j < 3; j++) {
        float v = ip[t + 128 * j];
        if (ip2) v += ip2[t + 128 * j];
        x[j] = v; s += v; s2 += v * v;
    }
    red[t] = s; red2[t] = s2; __syncthreads();
    for (int off = 64; off >= 1; off >>= 1) {
        if (t < off) { red[t] += red[t + off]; red2[t] += red2[t + off]; }
        __syncthreads();
    }
    float mu = red[0] * (1.f / 384.f);
    float var = red2[0] * (1.f / 384.f) - mu * mu;
    float rs = rsqrtf(var + EPSV);
    #pragma unroll
    for (int j = 0; j < 3; j++) {
        int c = t + 128 * j;
        out[(size_t)row * 384 + c] = (x[j] - mu) * rs * g[c] + b[c];
    }
}

// ---------------- mixer-final LN + positional add, scatter into x ----------------
__global__ __launch_bounds__(128) void build_x_kernel(
    const float* __restrict__ mix, const float* __restrict__ tc,
    const float* __restrict__ tg, const float* __restrict__ tb,
    const float* __restrict__ fpos, const float* __restrict__ ppos,
    float* __restrict__ x)
{
    int row = blockIdx.x;             // bp*32 + t, bp = b*16 + p
    int t = row & 31; int bp = row >> 5;
    int p = bp & 15; int b = bp >> 4;
    int tid = threadIdx.x;
    const float* ip = mix + (size_t)row * 384;
    const float* ip2 = tc + (size_t)row * 384;
    __shared__ float red[128], red2[128];
    float v[3]; float s = 0.f, s2 = 0.f;
    #pragma unroll
    for (int j = 0; j < 3; j++) {
        float val = ip[tid + 128 * j] + ip2[tid + 128 * j];
        v[j] = val; s += val; s2 += val * val;
    }
    red[tid] = s; red2[tid] = s2; __syncthreads();
    for (int off = 64; off >= 1; off >>= 1) {
        if (tid < off) { red[tid] += red[tid + off]; red2[tid] += red2[tid + off]; }
        __syncthreads();
    }
    float mu = red[0] * (1.f / 384.f);
    float var = red2[0] * (1.f / 384.f) - mu * mu;
    float rs = rsqrtf(var + EPSV);
    size_t xbase = ((size_t)b * 513 + 1 + t * 16 + p) * 384;
    #pragma unroll
    for (int j = 0; j < 3; j++) {
        int c = tid + 128 * j;
        float y = (v[j] - mu) * rs * tg[c] + tb[c] + fpos[t * 384 + c] + ppos[p * 384 + c];
        x[xbase + c] = y;
    }
}

__global__ __launch_bounds__(256) void cls_kernel(
    const float* __restrict__ ct, const float* __restrict__ cp, float* __restrict__ x)
{
    int idx = blockIdx.x * 256 + threadIdx.x;
    if (idx >= 8 * 384) return;
    int c = idx % 384; int b = idx / 384;
    x[(size_t)b * 513 * 384 + c] = ct[c] + cp[c];
}

// ---------------- fused masked attention: one block per (q-row, b*h) ----------------
__global__ __launch_bounds__(256) void attn_kernel(
    const float* __restrict__ qkv, float* __restrict__ out)
{
    int i = blockIdx.x;               // query index 0..512
    int bh = blockIdx.y; int h = bh % 6; int b = bh / 6;
    int tid = threadIdx.x;
    __shared__ float qs[64];
    __shared__ float ps[513];
    __shared__ float red[256];
    const float* qrow = qkv + ((size_t)(b * 513 + i) * 1152) + h * 64;
    if (tid < 64) qs[tid] = qrow[tid];
    __syncthreads();
    int fi = (i == 0) ? -1 : (i - 1) >> 4;   // query frame (-1: cls, attends all)
    float lmax = -INFINITY;
    for (int j = tid; j < 513; j += 256) {
        bool masked = (i != 0) && ((j == 0) || (((j - 1) >> 4) < fi));
        float sc;
        if (masked) sc = -INFINITY;
        else {
            const float* krow = qkv + ((size_t)(b * 513 + j) * 1152) + 384 + h * 64;
            float acc = 0.f;
            #pragma unroll
            for (int d = 0; d < 64; d++) acc += qs[d] * krow[d];
            sc = acc * 0.125f;
        }
        ps[j] = sc;
        lmax = fmaxf(lmax, sc);
    }
    red[tid] = lmax; __syncthreads();
    for (int off = 128; off >= 1; off >>= 1) {
        if (tid < off) red[tid] = fmaxf(red[tid], red[tid + off]);
        __syncthreads();
    }
    float mx = red[0]; __syncthreads();
    float lsum = 0.f;
    for (int j = tid; j < 513; j += 256) {
        float p = expf(ps[j] - mx);     // exp(-inf - mx) = 0 for masked
        ps[j] = p; lsum += p;
    }
    red[tid] = lsum; __syncthreads();
    for (int off = 128; off >= 1; off >>= 1) {
        if (tid < off) red[tid] += red[tid + off];
        __syncthreads();
    }
    float rsum = 1.0f / red[0];
    __syncthreads();
    // o[d] = (sum_j p_j * v[j][d]) * rsum   — 4 j-groups x 64 d
    int d = tid & 63; int jg = tid >> 6;
    float oacc = 0.f;
    for (int j = jg; j < 513; j += 4) {
        const float* vrow = qkv + ((size_t)(b * 513 + j) * 1152) + 768 + h * 64;
        oacc += ps[j] * vrow[d];
    }
    red[tid] = oacc; __syncthreads();
    if (tid < 64) {
        float o = red[tid] + red[tid + 64] + red[tid + 128] + red[tid + 192];
        out[((size_t)(b * 513 + i) * 384) + h * 64 + d] = o * rsum;
    }
}

// ---------------- head: LN + MLP(384->384 gelu ->2) + sigmoid ----------------
__global__ __launch_bounds__(128) void head_kernel(
    const float* __restrict__ x, const float* __restrict__ lg, const float* __restrict__ lb,
    const float* __restrict__ w1, const float* __restrict__ b1,
    const float* __restrict__ w2, const float* __restrict__ b2,
    float* __restrict__ out)
{
    int b = blockIdx.x; int t = threadIdx.x;
    __shared__ float hs[384], h1[384];
    __shared__ float red[128], red2[128];
    const float* xp = x + (size_t)b * 513 * 384;   // row 0 = cls
    float v[3]; float s = 0.f, s2 = 0.f;
    #pragma unroll
    for (int j = 0; j < 3; j++) {
        float val = xp[t + 128 * j];
        v[j] = val; s += val; s2 += val * val;
    }
    red[t] = s; red2[t] = s2; __syncthreads();
    for (int off = 64; off >= 1; off >>= 1) {
        if (t < off) { red[t] += red[t + off]; red2[t] += red2[t + off]; }
        __syncthreads();
    }
    float mu = red[0] * (1.f / 384.f);
    float var = red2[0] * (1.f / 384.f) - mu * mu;
    float rs = rsqrtf(var + EPSV);
    #pragma unroll
    for (int j = 0; j < 3; j++) {
        int c = t + 128 * j;
        hs[c] = (v[j] - mu) * rs * lg[c] + lb[c];
    }
    __syncthreads();
    #pragma unroll
    for (int j = 0; j < 3; j++) {
        int o = t + 128 * j;
        const float* wr = w1 + (size_t)o * 384;
        float acc = b1[o];
        for (int c = 0; c < 384; c++) acc += wr[c] * hs[c];
        h1[o] = gelu_f(acc);
    }
    __syncthreads();
    if (t < 2) {
        const float* wr = w2 + (size_t)t * 384;
        float acc = b2[t];
        for (int c = 0; c < 384; c++) acc += wr[c] * h1[c];
        out[b * 2 + t] = 1.f / (1.f + expf(-acc));
    }
}

static inline int cdiv(int a, int b) { return (a + b - 1) / b; }

extern "C" void kernel_launch(void* const* d_in, const int* in_sizes, int n_in,
                              void* d_out, int out_size, void* d_ws, size_t ws_size,
                              hipStream_t stream)
{
    const float* frames  = (const float*)d_in[0];
    const float* conv1_w = (const float*)d_in[1];
    const float* bn1_g = (const float*)d_in[2]; const float* bn1_b = (const float*)d_in[3];
    const float* bn1_m = (const float*)d_in[4]; const float* bn1_v = (const float*)d_in[5];
    const float* conv2_w = (const float*)d_in[6];
    const float* bn2_g = (const float*)d_in[7]; const float* bn2_b = (const float*)d_in[8];
    const float* bn2_m = (const float*)d_in[9]; const float* bn2_v = (const float*)d_in[10];
    const float* conv3_w = (const float*)d_in[11];
    const float* bn3_g = (const float*)d_in[12]; const float* bn3_b = (const float*)d_in[13];
    const float* bn3_m = (const float*)d_in[14]; const float* bn3_v = (const float*)d_in[15];
    const float* proj_w = (const float*)d_in[16];
    const float* dw_w = (const float*)d_in[17]; const float* dw_b = (const float*)d_in[18];
    const float* pw_w = (const float*)d_in[19]; const float* pw_b = (const float*)d_in[20];
    const float* tnorm_g = (const float*)d_in[21]; const float* tnorm_b = (const float*)d_in[22];
    const float* frame_pos = (const float*)d_in[23];
    const float* patch_pos = (const float*)d_in[24];
    const float* cls_token = (const float*)d_in[25];
    const float* cls_pos = (const float*)d_in[26];
    const float* qkv_w = (const float*)d_in[27]; const float* qkv_b = (const float*)d_in[28];
    const float* out_w = (const float*)d_in[29]; const float* out_b = (const float*)d_in[30];
    const float* ln1_g = (const float*)d_in[31]; const float* ln1_b = (const float*)d_in[32];
    const float* ln2_g = (const float*)d_in[33]; const float* ln2_b = (const float*)d_in[34];
    const float* ffn_w1 = (const float*)d_in[35]; const float* ffn_b1 = (const float*)d_in[36];
    const float* ffn_w2 = (const float*)d_in[37]; const float* ffn_b2 = (const float*)d_in[38];
    const float* head_ln_g = (const float*)d_in[39]; const float* head_ln_b = (const float*)d_in[40];
    const float* head_w1 = (const float*)d_in[41]; const float* head_b1 = (const float*)d_in[42];
    const float* head_w2 = (const float*)d_in[43]; const float* head_b2 = (const float*)d_in[44];

    float* ws = (float*)d_ws;
    size_t off = 0;
    auto alloc = [&](size_t n) { float* p = ws + off; off += (n + 63) & ~(size_t)63; return p; };

    float* tokens = alloc(256 * 16 * 384);        // persists conv->mixer
    size_t arena_start = off;
    float* c1 = alloc((size_t)64 * 32 * 64 * 64);
    float* c2 = alloc((size_t)64 * 64 * 32 * 32);
    float* c3 = alloc((size_t)64 * 128 * 16 * 16);
    float* poolT = alloc((size_t)64 * 16 * 128);
    size_t arena_end = off;
    // mixer buffers alias the conv arena (conv done before mixer starts)
    off = arena_start;
    float* tc = alloc(128 * 32 * 384);
    float* mA = alloc(128 * 32 * 384);
    float* mB = alloc(128 * 32 * 384);
    float* mh = alloc(128 * 32 * 384);
    off = arena_end;
    float* xb   = alloc((size_t)8 * 513 * 384);
    float* hb   = alloc((size_t)8 * 513 * 384);
    float* qkvb = alloc((size_t)8 * 513 * 1152);
    float* ob   = alloc((size_t)8 * 513 * 384);
    float* ffb  = alloc((size_t)8 * 513 * 1536);
    (void)ws_size; (void)in_sizes; (void)n_in; (void)out_size;

    // ---------- conv stem, 4 chunks of 64 frames ----------
    const int NC = 64;
    for (int ch = 0; ch < 4; ch++) {
        const float* fch = frames + (size_t)ch * NC * 16384;
        conv1_kernel<<<cdiv(NC * 32 * 64 * 64, 256), 256, 0, stream>>>(
            fch, conv1_w, bn1_g, bn1_b, bn1_m, bn1_v, c1, NC);
        conv3x3s2_kernel<32, 64><<<cdiv(NC * 64 * 32 * 32, 256), 256, 0, stream>>>(
            c1, conv2_w, bn2_g, bn2_b, bn2_m, bn2_v, c2, NC, 64);
        conv3x3s2_kernel<64, 32><<<cdiv(NC * 128 * 16 * 16, 256), 256, 0, stream>>>(
            c2, conv3_w, bn3_g, bn3_b, bn3_m, bn3_v, c3, NC, 128);
        pool_kernel<<<cdiv(NC * 16 * 128, 256), 256, 0, stream>>>(c3, poolT, NC);
        // tokens_chunk[M=1024, 384] = poolT[1024,128] @ proj_w[384,128]^T
        dim3 pg(384 / GBN, cdiv(NC * 16, GBM));
        gemm_nt_kernel<<<pg, 256, 0, stream>>>(
            poolT, proj_w, nullptr, nullptr,
            tokens + (size_t)ch * NC * 16 * 384, NC * 16, 384, 128, 0);
    }

    // ---------- temporal mixer ----------
    tok2tc_kernel<<<cdiv(8 * 32 * 16 * 384, 256), 256, 0, stream>>>(tokens, tc);
    hipMemcpyAsync(mA, tc, (size_t)128 * 32 * 384 * sizeof(float),
                   hipMemcpyDeviceToDevice, stream);
    float* cur = mA; float* alt = mB;
    for (int it = 0; it < 2; it++) {
        int dil = (it == 0) ? 1 : 2;
        dwconv_kernel<<<cdiv(128 * 32 * 384, 256), 256, 0, stream>>>(
            cur, dw_w + (size_t)it * 384 * 3, dw_b + (size_t)it * 384, mh, dil);
        dim3 pg(384 / GBN, cdiv(128 * 32, GBM));
        gemm_nt_kernel<<<pg, 256, 0, stream>>>(
            mh, pw_w + (size_t)it * 384 * 384, pw_b + (size_t)it * 384, cur,
            alt, 128 * 32, 384, 384, 0);
        float* tmp = cur; cur = alt; alt = tmp;
    }

    // ---------- build transformer input x ----------
    build_x_kernel<<<128 * 32, 128, 0, stream>>>(
        cur, tc, tnorm_g, tnorm_b, frame_pos, patch_pos, xb);
    cls_kernel<<<cdiv(8 * 384, 256), 256, 0, stream>>>(cls_token, cls_pos, xb);

    // ---------- transformer ----------
    const int M = 8 * 513;   // 4104
    for (int l = 0; l < 6; l++) {
        ln_kernel<<<M, 128, 0, stream>>>(xb, nullptr,
            ln1_g + (size_t)l * 384, ln1_b + (size_t)l * 384, hb, M);
        {
            dim3 pg(1152 / GBN, cdiv(M, GBM));
            gemm_nt_kernel<<<pg, 256, 0, stream>>>(
                hb, qkv_w + (size_t)l * 1152 * 384, qkv_b + (size_t)l * 1152,
                nullptr, qkvb, M, 1152, 384, 0);
        }
        {
            dim3 ag(513, 48);
            attn_kernel<<<ag, 256, 0, stream>>>(qkvb, ob);
        }
        {
            dim3 pg(384 / GBN, cdiv(M, GBM));
            gemm_nt_kernel<<<pg, 256, 0, stream>>>(
                ob, out_w + (size_t)l * 384 * 384, out_b + (size_t)l * 384,
                xb, xb, M, 384, 384, 0);
        }
        ln_kernel<<<M, 128, 0, stream>>>(xb, nullptr,
            ln2_g + (size_t)l * 384, ln2_b + (size_t)l * 384, hb, M);
        {
            dim3 pg(1536 / GBN, cdiv(M, GBM));
            gemm_nt_kernel<<<pg, 256, 0, stream>>>(
                hb, ffn_w1 + (size_t)l * 1536 * 384, ffn_b1 + (size_t)l * 1536,
                nullptr, ffb, M, 1536, 384, 1);
        }
        {
            dim3 pg(384 / GBN, cdiv(M, GBM));
            gemm_nt_kernel<<<pg, 256, 0, stream>>>(
                ffb, ffn_w2 + (size_t)l * 384 * 1536, ffn_b2 + (size_t)l * 384,
                xb, xb, M, 384, 1536, 0);
        }
    }

    // ---------- head ----------
    head_kernel<<<8, 128, 0, stream>>>(
        xb, head_ln_g, head_ln_b, head_w1, head_b1, head_w2, head_b2, (float*)d_out);
}

// Round 2
// 8834.119 us; speedup vs baseline: 1.3582x; 1.3582x over previous
//
#include <hip/hip_runtime.h>
#include <cstddef>

#define EPSV 1e-5f

__device__ __forceinline__ float gelu_f(float x) {
    return 0.5f * x * (1.0f + erff(x * 0.7071067811865476f));
}

// ---------------- conv1: 5x5 stride2 pad2, CI=1, CO=32, 128->64 ----------------
__global__ __launch_bounds__(256) void conv1_kernel(
    const float* __restrict__ in, const float* __restrict__ w,
    const float* __restrict__ g, const float* __restrict__ bt,
    const float* __restrict__ mn, const float* __restrict__ vr,
    float* __restrict__ out, int N)
{
    int idx = blockIdx.x * 256 + threadIdx.x;
    if (idx >= N * 32 * 64 * 64) return;
    int ox = idx & 63, oy = (idx >> 6) & 63, co = (idx >> 12) & 31, n = idx >> 17;
    const float* ip = in + (size_t)n * 16384;
    const float* wp = w + co * 25;
    int iy0 = oy * 2 - 2, ix0 = ox * 2 - 2;
    float acc = 0.f;
    #pragma unroll
    for (int ky = 0; ky < 5; ky++) {
        int iy = iy0 + ky;
        if ((unsigned)iy >= 128u) continue;
        #pragma unroll
        for (int kx = 0; kx < 5; kx++) {
            int ix = ix0 + kx;
            if ((unsigned)ix >= 128u) continue;
            acc += wp[ky * 5 + kx] * ip[iy * 128 + ix];
        }
    }
    float inv = g[co] * rsqrtf(vr[co] + EPSV);
    acc = acc * inv + (bt[co] - mn[co] * inv);
    out[idx] = gelu_f(acc);
}

// ---------------- conv 3x3 stride2 pad1 generic (templated CI, HI) ----------------
template<int CI, int HI>
__global__ __launch_bounds__(256) void conv3x3s2_kernel(
    const float* __restrict__ in, const float* __restrict__ w,
    const float* __restrict__ g, const float* __restrict__ bt,
    const float* __restrict__ mn, const float* __restrict__ vr,
    float* __restrict__ out, int N, int CO)
{
    constexpr int HO = HI / 2;
    int idx = blockIdx.x * 256 + threadIdx.x;
    if (idx >= N * CO * HO * HO) return;
    int ox = idx % HO; int t = idx / HO;
    int oy = t % HO; t /= HO;
    int co = t % CO; int n = t / CO;
    const float* wp = w + (size_t)co * (CI * 9);
    const float* ip = in + (size_t)n * (CI * HI * HI);
    int iy0 = oy * 2 - 1, ix0 = ox * 2 - 1;
    float acc = 0.f;
    for (int ci = 0; ci < CI; ci++) {
        const float* ipc = ip + ci * HI * HI;
        const float* wpc = wp + ci * 9;
        #pragma unroll
        for (int ky = 0; ky < 3; ky++) {
            int iy = iy0 + ky;
            if ((unsigned)iy >= (unsigned)HI) continue;
            #pragma unroll
            for (int kx = 0; kx < 3; kx++) {
                int ix = ix0 + kx;
                if ((unsigned)ix >= (unsigned)HI) continue;
                acc += wpc[ky * 3 + kx] * ipc[iy * HI + ix];
            }
        }
    }
    float inv = g[co] * rsqrtf(vr[co] + EPSV);
    acc = acc * inv + (bt[co] - mn[co] * inv);
    out[idx] = gelu_f(acc);
}

// ---------------- 4x4 avg-pool (16x16 -> 4x4) + transpose to (n, p, c) ----------------
__global__ __launch_bounds__(256) void pool_kernel(
    const float* __restrict__ in, float* __restrict__ out, int N)
{
    int idx = blockIdx.x * 256 + threadIdx.x;
    if (idx >= N * 16 * 128) return;
    int c = idx & 127; int p = (idx >> 7) & 15; int n = idx >> 11;
    int ph = p >> 2, pw = p & 3;
    const float* ip = in + (((size_t)n * 128 + c) * 16 + ph * 4) * 16 + pw * 4;
    float s = 0.f;
    #pragma unroll
    for (int dy = 0; dy < 4; dy++)
        #pragma unroll
        for (int dx = 0; dx < 4; dx++)
            s += ip[dy * 16 + dx];
    out[idx] = s * 0.0625f;
}

// ---------------- big NT SGEMM: C = [res +] act(A[M,K] @ B[N,K]^T + bias) ----------------
// tile 128x64, 256 threads, 8x4 microtile. N%64==0, K%16==0; M guarded.
#define TBM 128
#define TBN 64
#define TBK 16
__global__ __launch_bounds__(256) void gemm_big_kernel(
    const float* __restrict__ A, const float* __restrict__ B,
    const float* __restrict__ bias, const float* __restrict__ res,
    float* __restrict__ C, int M, int N, int K, int act)
{
    __shared__ __align__(16) float As[TBK][TBM + 4];
    __shared__ __align__(16) float Bs[TBK][TBN + 4];
    int tid = threadIdx.x;
    int bm = blockIdx.y * TBM;
    int bn = blockIdx.x * TBN;
    int tx = tid & 15, ty = tid >> 4;
    int ar = tid >> 1, ak = (tid & 1) * 8;   // A: 2 float4 per thread
    int br = tid >> 2, bk = (tid & 3) * 4;   // B: 1 float4 per thread
    float acc[8][4] = {};
    for (int k0 = 0; k0 < K; k0 += TBK) {
        float ra[8];
        {
            int row = bm + ar;
            if (row < M) {
                *reinterpret_cast<float4*>(ra + 0) = *reinterpret_cast<const float4*>(A + (size_t)row * K + k0 + ak);
                *reinterpret_cast<float4*>(ra + 4) = *reinterpret_cast<const float4*>(A + (size_t)row * K + k0 + ak + 4);
            } else {
                #pragma unroll
                for (int u = 0; u < 8; u++) ra[u] = 0.f;
            }
        }
        float rb[4];
        {
            int row = bn + br;
            if (row < N) *reinterpret_cast<float4*>(rb) = *reinterpret_cast<const float4*>(B + (size_t)row * K + k0 + bk);
            else { rb[0] = rb[1] = rb[2] = rb[3] = 0.f; }
        }
        #pragma unroll
        for (int u = 0; u < 8; u++) As[ak + u][ar] = ra[u];
        #pragma unroll
        for (int u = 0; u < 4; u++) Bs[bk + u][br] = rb[u];
        __syncthreads();
        #pragma unroll
        for (int k = 0; k < TBK; k++) {
            float4 a0 = *reinterpret_cast<const float4*>(&As[k][ty * 8]);
            float4 a1 = *reinterpret_cast<const float4*>(&As[k][ty * 8 + 4]);
            float4 bv = *reinterpret_cast<const float4*>(&Bs[k][tx * 4]);
            float av[8] = {a0.x, a0.y, a0.z, a0.w, a1.x, a1.y, a1.z, a1.w};
            float bw[4] = {bv.x, bv.y, bv.z, bv.w};
            #pragma unroll
            for (int i = 0; i < 8; i++)
                #pragma unroll
                for (int j = 0; j < 4; j++)
                    acc[i][j] += av[i] * bw[j];
        }
        __syncthreads();
    }
    #pragma unroll
    for (int i = 0; i < 8; i++) {
        int row = bm + ty * 8 + i;
        if (row >= M) continue;
        #pragma unroll
        for (int j = 0; j < 4; j++) {
            int col = bn + tx * 4 + j;
            float v = acc[i][j];
            if (bias) v += bias[col];
            if (act == 1) v = gelu_f(v);
            if (res) v += res[(size_t)row * N + col];
            C[(size_t)row * N + col] = v;
        }
    }
}

// ---------------- tokens (b,t,p,d) -> tc (b*16+p, t, d) ----------------
__global__ __launch_bounds__(256) void tok2tc_kernel(
    const float* __restrict__ in, float* __restrict__ out)
{
    int idx = blockIdx.x * 256 + threadIdx.x;
    if (idx >= 8 * 32 * 16 * 384) return;
    int d = idx % 384; int t2 = idx / 384;
    int p = t2 & 15; t2 >>= 4;
    int t = t2 & 31; int b = t2 >> 5;
    out[(((size_t)(b * 16 + p) * 32 + t) * 384) + d] = in[idx];
}

// ---------------- depthwise temporal conv (k=3, dilation dil) + bias + gelu ----------------
__global__ __launch_bounds__(256) void dwconv_kernel(
    const float* __restrict__ in, const float* __restrict__ w,
    const float* __restrict__ bias, float* __restrict__ out, int dil)
{
    int idx = blockIdx.x * 256 + threadIdx.x;
    if (idx >= 128 * 32 * 384) return;
    int d = idx % 384; int t = (idx / 384) & 31; int s = idx / (384 * 32);
    const float* ip = in + (size_t)s * 32 * 384 + d;
    float acc = bias[d];
    #pragma unroll
    for (int k = 0; k < 3; k++) {
        int tt = t + (k - 1) * dil;
        if ((unsigned)tt < 32u) acc += w[d * 3 + k] * ip[tt * 384];
    }
    out[idx] = gelu_f(acc);
}

// ---------------- generic LayerNorm over last dim 384 ----------------
__global__ __launch_bounds__(128) void ln_kernel(
    const float* __restrict__ in, const float* __restrict__ in2,
    const float* __restrict__ g, const float* __restrict__ b,
    float* __restrict__ out, int rows)
{
    int row = blockIdx.x;
    if (row >= rows) return;
    int t = threadIdx.x;
    const float* ip = in + (size_t)row * 384;
    const float* ip2 = in2 ? in2 + (size_t)row * 384 : nullptr;
    __shared__ float red[128], red2[128];
    float x[3]; float s = 0.f, s2 = 0.f;
    #pragma unroll
    for (int j = 0; j < 3; j++) {
        float v = ip[t + 128 * j];
        if (ip2) v += ip2[t + 128 * j];
        x[j] = v; s += v; s2 += v * v;
    }
    red[t] = s; red2[t] = s2; __syncthreads();
    for (int off = 64; off >= 1; off >>= 1) {
        if (t < off) { red[t] += red[t + off]; red2[t] += red2[t + off]; }
        __syncthreads();
    }
    float mu = red[0] * (1.f / 384.f);
    float var = red2[0] * (1.f / 384.f) - mu * mu;
    float rs = rsqrtf(var + EPSV);
    #pragma unroll
    for (int j = 0; j < 3; j++) {
        int c = t + 128 * j;
        out[(size_t)row * 384 + c] = (x[j] - mu) * rs * g[c] + b[c];
    }
}

// ---------------- mixer-final LN + positional add, scatter into x ----------------
__global__ __launch_bounds__(128) void build_x_kernel(
    const float* __restrict__ mix, const float* __restrict__ tc,
    const float* __restrict__ tg, const float* __restrict__ tb,
    const float* __restrict__ fpos, const float* __restrict__ ppos,
    float* __restrict__ x)
{
    int row = blockIdx.x;             // bp*32 + t, bp = b*16 + p
    int t = row & 31; int bp = row >> 5;
    int p = bp & 15; int b = bp >> 4;
    int tid = threadIdx.x;
    const float* ip = mix + (size_t)row * 384;
    const float* ip2 = tc + (size_t)row * 384;
    __shared__ float red[128], red2[128];
    float v[3]; float s = 0.f, s2 = 0.f;
    #pragma unroll
    for (int j = 0; j < 3; j++) {
        float val = ip[tid + 128 * j] + ip2[tid + 128 * j];
        v[j] = val; s += val; s2 += val * val;
    }
    red[tid] = s; red2[tid] = s2; __syncthreads();
    for (int off = 64; off >= 1; off >>= 1) {
        if (tid < off) { red[tid] += red[tid + off]; red2[tid] += red2[tid + off]; }
        __syncthreads();
    }
    float mu = red[0] * (1.f / 384.f);
    float var = red2[0] * (1.f / 384.f) - mu * mu;
    float rs = rsqrtf(var + EPSV);
    size_t xbase = ((size_t)b * 513 + 1 + t * 16 + p) * 384;
    #pragma unroll
    for (int j = 0; j < 3; j++) {
        int c = tid + 128 * j;
        float y = (v[j] - mu) * rs * tg[c] + tb[c] + fpos[t * 384 + c] + ppos[p * 384 + c];
        x[xbase + c] = y;
    }
}

__global__ __launch_bounds__(256) void cls_kernel(
    const float* __restrict__ ct, const float* __restrict__ cp, float* __restrict__ x)
{
    int idx = blockIdx.x * 256 + threadIdx.x;
    if (idx >= 8 * 384) return;
    int c = idx % 384; int b = idx / 384;
    x[(size_t)b * 513 * 384 + c] = ct[c] + cp[c];
}

// ---------------- flash attention: block = (q-tile 64, b*h), 256 threads ----------------
// qkv rows: [Q(384) K(384) V(384)]; S=513, hd=64, scale=0.125
__global__ __launch_bounds__(256) void fattn_kernel(
    const float* __restrict__ qkv, float* __restrict__ out)
{
    __shared__ __align__(16) float Qs[64][65];   // [d][q]
    __shared__ __align__(16) float KVs[64][65];  // K phase: [d][j]; V phase: [j][d]
    __shared__ __align__(16) float Ps[64][65];   // [j][q]
    __shared__ float red[64][16];

    int qt = blockIdx.x;               // 0..8
    int bh = blockIdx.y; int h = bh % 6; int b = bh / 6;
    int tid = threadIdx.x;
    int tx = tid & 15, ty = tid >> 4;
    int lr = tid >> 2, lc = (tid & 3) * 16;   // loader: row lr (0..63), 16-float chunk lc
    int q0 = qt * 64;
    const size_t RS = 1152;
    const float* base = qkv + (size_t)(b * 513) * RS + h * 64;

    // ---- load Q tile transposed into Qs[d][q] ----
    {
        float rq[16];
        int qi = q0 + lr;
        if (qi < 513) {
            const float* p = base + (size_t)qi * RS + lc;
            *reinterpret_cast<float4*>(rq + 0)  = *reinterpret_cast<const float4*>(p + 0);
            *reinterpret_cast<float4*>(rq + 4)  = *reinterpret_cast<const float4*>(p + 4);
            *reinterpret_cast<float4*>(rq + 8)  = *reinterpret_cast<const float4*>(p + 8);
            *reinterpret_cast<float4*>(rq + 12) = *reinterpret_cast<const float4*>(p + 12);
        } else {
            #pragma unroll
            for (int u = 0; u < 16; u++) rq[u] = 0.f;
        }
        #pragma unroll
        for (int u = 0; u < 16; u++) Qs[lc + u][lr] = rq[u];
    }

    float O[4][4] = {};
    float m[4], l[4];
    #pragma unroll
    for (int i = 0; i < 4; i++) { m[i] = -INFINITY; l[i] = 0.f; }

    int jt0 = 0;
    if (qt > 0) {
        int fmin = (q0 - 1) >> 4;           // min query frame in tile
        jt0 = (fmin * 16 + 1) >> 6;         // first j-tile with any unmasked key
    }

    for (int jt = jt0; jt < 9; jt++) {
        int j0 = jt * 64;
        __syncthreads();   // KVs free (prev PV done); Qs ready on first iter
        // ---- stage K tile transposed: KVs[d][j] ----
        {
            float rk[16];
            int j = j0 + lr;
            if (j < 513) {
                const float* p = base + (size_t)j * RS + 384 + lc;
                *reinterpret_cast<float4*>(rk + 0)  = *reinterpret_cast<const float4*>(p + 0);
                *reinterpret_cast<float4*>(rk + 4)  = *reinterpret_cast<const float4*>(p + 4);
                *reinterpret_cast<float4*>(rk + 8)  = *reinterpret_cast<const float4*>(p + 8);
                *reinterpret_cast<float4*>(rk + 12) = *reinterpret_cast<const float4*>(p + 12);
            } else {
                #pragma unroll
                for (int u = 0; u < 16; u++) rk[u] = 0.f;
            }
            #pragma unroll
            for (int u = 0; u < 16; u++) KVs[lc + u][lr] = rk[u];
        }
        // ---- prefetch V tile into regs (consumed after stats) ----
        float rv[16];
        {
            int j = j0 + lr;
            if (j < 513) {
                const float* p = base + (size_t)j * RS + 768 + lc;
                *reinterpret_cast<float4*>(rv + 0)  = *reinterpret_cast<const float4*>(p + 0);
                *reinterpret_cast<float4*>(rv + 4)  = *reinterpret_cast<const float4*>(p + 4);
                *reinterpret_cast<float4*>(rv + 8)  = *reinterpret_cast<const float4*>(p + 8);
                *reinterpret_cast<float4*>(rv + 12) = *reinterpret_cast<const float4*>(p + 12);
            } else {
                #pragma unroll
                for (int u = 0; u < 16; u++) rv[u] = 0.f;
            }
        }
        __syncthreads();   // K staged

        // ---- QK^T micro: s[4q][4j] ----
        float s[4][4] = {};
        #pragma unroll 8
        for (int d = 0; d < 64; d++) {
            float4 qv = *reinterpret_cast<const float4*>(&Qs[d][ty * 4]);
            float4 kv = *reinterpret_cast<const float4*>(&KVs[d][tx * 4]);
            float qa[4] = {qv.x, qv.y, qv.z, qv.w};
            float ka[4] = {kv.x, kv.y, kv.z, kv.w};
            #pragma unroll
            for (int i = 0; i < 4; i++)
                #pragma unroll
                for (int jj = 0; jj < 4; jj++)
                    s[i][jj] += qa[i] * ka[jj];
        }
        // ---- mask + scale ----
        #pragma unroll
        for (int i = 0; i < 4; i++) {
            int qi = q0 + ty * 4 + i;
            int fi = (qi == 0) ? -1 : ((qi - 1) >> 4);
            #pragma unroll
            for (int jj = 0; jj < 4; jj++) {
                int j = j0 + tx * 4 + jj;
                bool valid = (qi < 513) && (j < 513) &&
                             !((qi != 0) && ((j == 0) || (((j - 1) >> 4) < fi)));
                s[i][jj] = valid ? s[i][jj] * 0.125f : -INFINITY;
            }
        }
        // ---- row max across tx ----
        #pragma unroll
        for (int i = 0; i < 4; i++) {
            float tm = fmaxf(fmaxf(s[i][0], s[i][1]), fmaxf(s[i][2], s[i][3]));
            red[ty * 4 + i][tx] = tm;
        }
        __syncthreads();
        float mnew[4], alpha[4], lpart[4];
        #pragma unroll
        for (int i = 0; i < 4; i++) {
            int r = ty * 4 + i;
            float mt = -INFINITY;
            #pragma unroll
            for (int t = 0; t < 16; t++) mt = fmaxf(mt, red[r][t]);
            mnew[i] = fmaxf(m[i], mt);
            alpha[i] = (m[i] == -INFINITY) ? 0.f : __expf(m[i] - mnew[i]);
            float lp = 0.f;
            #pragma unroll
            for (int jj = 0; jj < 4; jj++) {
                float p = (s[i][jj] == -INFINITY) ? 0.f : __expf(s[i][jj] - mnew[i]);
                s[i][jj] = p; lp += p;
            }
            lpart[i] = lp;
        }
        __syncthreads();   // red readers done; QK micro done -> KVs reusable
        #pragma unroll
        for (int i = 0; i < 4; i++) {
            red[ty * 4 + i][tx] = lpart[i];
            #pragma unroll
            for (int jj = 0; jj < 4; jj++)
                Ps[tx * 4 + jj][ty * 4 + i] = s[i][jj];
        }
        // V regs -> KVs[j][d] (natural layout, vector stores)
        {
            #pragma unroll
            for (int u = 0; u < 4; u++)
                *reinterpret_cast<float4*>(&KVs[lr][lc + u * 4]) = *reinterpret_cast<float4*>(rv + u * 4);
        }
        __syncthreads();   // Ps, V, l-partials visible
        #pragma unroll
        for (int i = 0; i < 4; i++) {
            int r = ty * 4 + i;
            float lt = 0.f;
            #pragma unroll
            for (int t = 0; t < 16; t++) lt += red[r][t];
            l[i] = alpha[i] * l[i] + lt;
            m[i] = mnew[i];
        }
        // ---- PV micro: O[4q][4d] (ty=q/4, tx=d/4) ----
        #pragma unroll
        for (int i = 0; i < 4; i++)
            #pragma unroll
            for (int dd = 0; dd < 4; dd++)
                O[i][dd] *= alpha[i];
        #pragma unroll 8
        for (int j = 0; j < 64; j++) {
            float4 pv = *reinterpret_cast<const float4*>(&Ps[j][ty * 4]);
            float4 vv = *reinterpret_cast<const float4*>(&KVs[j][tx * 4]);
            float pa[4] = {pv.x, pv.y, pv.z, pv.w};
            float va[4] = {vv.x, vv.y, vv.z, vv.w};
            #pragma unroll
            for (int i = 0; i < 4; i++)
                #pragma unroll
                for (int dd = 0; dd < 4; dd++)
                    O[i][dd] += pa[i] * va[dd];
        }
    }

    // ---- write out ----
    #pragma unroll
    for (int i = 0; i < 4; i++) {
        int qi = q0 + ty * 4 + i;
        if (qi >= 513) continue;
        float rl = 1.0f / l[i];
        float* op = out + ((size_t)(b * 513 + qi)) * 384 + h * 64 + tx * 4;
        #pragma unroll
        for (int dd = 0; dd < 4; dd++) op[dd] = O[i][dd] * rl;
    }
}

// ---------------- head: LN + MLP(384->384 gelu ->2) + sigmoid ----------------
__global__ __launch_bounds__(128) void head_kernel(
    const float* __restrict__ x, const float* __restrict__ lg, const float* __restrict__ lb,
    const float* __restrict__ w1, const float* __restrict__ b1,
    const float* __restrict__ w2, const float* __restrict__ b2,
    float* __restrict__ out)
{
    int b = blockIdx.x; int t = threadIdx.x;
    __shared__ float hs[384], h1[384];
    __shared__ float red[128], red2[128];
    const float* xp = x + (size_t)b * 513 * 384;   // row 0 = cls
    float v[3]; float s = 0.f, s2 = 0.f;
    #pragma unroll
    for (int j = 0; j < 3; j++) {
        float val = xp[t + 128 * j];
        v[j] = val; s += val; s2 += val * val;
    }
    red[t] = s; red2[t] = s2; __syncthreads();
    for (int off = 64; off >= 1; off >>= 1) {
        if (t < off) { red[t] += red[t + off]; red2[t] += red2[t + off]; }
        __syncthreads();
    }
    float mu = red[0] * (1.f / 384.f);
    float var = red2[0] * (1.f / 384.f) - mu * mu;
    float rs = rsqrtf(var + EPSV);
    #pragma unroll
    for (int j = 0; j < 3; j++) {
        int c = t + 128 * j;
        hs[c] = (v[j] - mu) * rs * lg[c] + lb[c];
    }
    __syncthreads();
    #pragma unroll
    for (int j = 0; j < 3; j++) {
        int o = t + 128 * j;
        const float* wr = w1 + (size_t)o * 384;
        float acc = b1[o];
        for (int c = 0; c < 384; c++) acc += wr[c] * hs[c];
        h1[o] = gelu_f(acc);
    }
    __syncthreads();
    if (t < 2) {
        const float* wr = w2 + (size_t)t * 384;
        float acc = b2[t];
        for (int c = 0; c < 384; c++) acc += wr[c] * h1[c];
        out[b * 2 + t] = 1.f / (1.f + expf(-acc));
    }
}

static inline int cdiv(int a, int b) { return (a + b - 1) / b; }

extern "C" void kernel_launch(void* const* d_in, const int* in_sizes, int n_in,
                              void* d_out, int out_size, void* d_ws, size_t ws_size,
                              hipStream_t stream)
{
    const float* frames  = (const float*)d_in[0];
    const float* conv1_w = (const float*)d_in[1];
    const float* bn1_g = (const float*)d_in[2]; const float* bn1_b = (const float*)d_in[3];
    const float* bn1_m = (const float*)d_in[4]; const float* bn1_v = (const float*)d_in[5];
    const float* conv2_w = (const float*)d_in[6];
    const float* bn2_g = (const float*)d_in[7]; const float* bn2_b = (const float*)d_in[8];
    const float* bn2_m = (const float*)d_in[9]; const float* bn2_v = (const float*)d_in[10];
    const float* conv3_w = (const float*)d_in[11];
    const float* bn3_g = (const float*)d_in[12]; const float* bn3_b = (const float*)d_in[13];
    const float* bn3_m = (const float*)d_in[14]; const float* bn3_v = (const float*)d_in[15];
    const float* proj_w = (const float*)d_in[16];
    const float* dw_w = (const float*)d_in[17]; const float* dw_b = (const float*)d_in[18];
    const float* pw_w = (const float*)d_in[19]; const float* pw_b = (const float*)d_in[20];
    const float* tnorm_g = (const float*)d_in[21]; const float* tnorm_b = (const float*)d_in[22];
    const float* frame_pos = (const float*)d_in[23];
    const float* patch_pos = (const float*)d_in[24];
    const float* cls_token = (const float*)d_in[25];
    const float* cls_pos = (const float*)d_in[26];
    const float* qkv_w = (const float*)d_in[27]; const float* qkv_b = (const float*)d_in[28];
    const float* out_w = (const float*)d_in[29]; const float* out_b = (const float*)d_in[30];
    const float* ln1_g = (const float*)d_in[31]; const float* ln1_b = (const float*)d_in[32];
    const float* ln2_g = (const float*)d_in[33]; const float* ln2_b = (const float*)d_in[34];
    const float* ffn_w1 = (const float*)d_in[35]; const float* ffn_b1 = (const float*)d_in[36];
    const float* ffn_w2 = (const float*)d_in[37]; const float* ffn_b2 = (const float*)d_in[38];
    const float* head_ln_g = (const float*)d_in[39]; const float* head_ln_b = (const float*)d_in[40];
    const float* head_w1 = (const float*)d_in[41]; const float* head_b1 = (const float*)d_in[42];
    const float* head_w2 = (const float*)d_in[43]; const float* head_b2 = (const float*)d_in[44];

    float* ws = (float*)d_ws;
    size_t off = 0;
    auto alloc = [&](size_t n) { float* p = ws + off; off += (n + 63) & ~(size_t)63; return p; };

    float* tokens = alloc(256 * 16 * 384);        // persists conv->mixer
    size_t arena_start = off;
    float* c1 = alloc((size_t)64 * 32 * 64 * 64);
    float* c2 = alloc((size_t)64 * 64 * 32 * 32);
    float* c3 = alloc((size_t)64 * 128 * 16 * 16);
    float* poolT = alloc((size_t)64 * 16 * 128);
    size_t arena_end = off;
    // mixer buffers alias the conv arena (conv done before mixer starts)
    off = arena_start;
    float* tc = alloc(128 * 32 * 384);
    float* mA = alloc(128 * 32 * 384);
    float* mB = alloc(128 * 32 * 384);
    float* mh = alloc(128 * 32 * 384);
    off = arena_end;
    float* xb   = alloc((size_t)8 * 513 * 384);
    float* hb   = alloc((size_t)8 * 513 * 384);
    float* qkvb = alloc((size_t)8 * 513 * 1152);
    float* ob   = alloc((size_t)8 * 513 * 384);
    float* ffb  = alloc((size_t)8 * 513 * 1536);
    (void)ws_size; (void)in_sizes; (void)n_in; (void)out_size;

    // ---------- conv stem, 4 chunks of 64 frames ----------
    const int NC = 64;
    for (int ch = 0; ch < 4; ch++) {
        const float* fch = frames + (size_t)ch * NC * 16384;
        conv1_kernel<<<cdiv(NC * 32 * 64 * 64, 256), 256, 0, stream>>>(
            fch, conv1_w, bn1_g, bn1_b, bn1_m, bn1_v, c1, NC);
        conv3x3s2_kernel<32, 64><<<cdiv(NC * 64 * 32 * 32, 256), 256, 0, stream>>>(
            c1, conv2_w, bn2_g, bn2_b, bn2_m, bn2_v, c2, NC, 64);
        conv3x3s2_kernel<64, 32><<<cdiv(NC * 128 * 16 * 16, 256), 256, 0, stream>>>(
            c2, conv3_w, bn3_g, bn3_b, bn3_m, bn3_v, c3, NC, 128);
        pool_kernel<<<cdiv(NC * 16 * 128, 256), 256, 0, stream>>>(c3, poolT, NC);
        dim3 pg(384 / TBN, cdiv(NC * 16, TBM));
        gemm_big_kernel<<<pg, 256, 0, stream>>>(
            poolT, proj_w, nullptr, nullptr,
            tokens + (size_t)ch * NC * 16 * 384, NC * 16, 384, 128, 0);
    }

    // ---------- temporal mixer ----------
    tok2tc_kernel<<<cdiv(8 * 32 * 16 * 384, 256), 256, 0, stream>>>(tokens, tc);
    hipMemcpyAsync(mA, tc, (size_t)128 * 32 * 384 * sizeof(float),
                   hipMemcpyDeviceToDevice, stream);
    float* cur = mA; float* alt = mB;
    for (int it = 0; it < 2; it++) {
        int dil = (it == 0) ? 1 : 2;
        dwconv_kernel<<<cdiv(128 * 32 * 384, 256), 256, 0, stream>>>(
            cur, dw_w + (size_t)it * 384 * 3, dw_b + (size_t)it * 384, mh, dil);
        dim3 pg(384 / TBN, cdiv(128 * 32, TBM));
        gemm_big_kernel<<<pg, 256, 0, stream>>>(
            mh, pw_w + (size_t)it * 384 * 384, pw_b + (size_t)it * 384, cur,
            alt, 128 * 32, 384, 384, 0);
        float* tmp = cur; cur = alt; alt = tmp;
    }

    // ---------- build transformer input x ----------
    build_x_kernel<<<128 * 32, 128, 0, stream>>>(
        cur, tc, tnorm_g, tnorm_b, frame_pos, patch_pos, xb);
    cls_kernel<<<cdiv(8 * 384, 256), 256, 0, stream>>>(cls_token, cls_pos, xb);

    // ---------- transformer ----------
    const int M = 8 * 513;   // 4104
    for (int l = 0; l < 6; l++) {
        ln_kernel<<<M, 128, 0, stream>>>(xb, nullptr,
            ln1_g + (size_t)l * 384, ln1_b + (size_t)l * 384, hb, M);
        {
            dim3 pg(1152 / TBN, cdiv(M, TBM));
            gemm_big_kernel<<<pg, 256, 0, stream>>>(
                hb, qkv_w + (size_t)l * 1152 * 384, qkv_b + (size_t)l * 1152,
                nullptr, qkvb, M, 1152, 384, 0);
        }
        {
            dim3 ag(9, 48);
            fattn_kernel<<<ag, 256, 0, stream>>>(qkvb, ob);
        }
        {
            dim3 pg(384 / TBN, cdiv(M, TBM));
            gemm_big_kernel<<<pg, 256, 0, stream>>>(
                ob, out_w + (size_t)l * 384 * 384, out_b + (size_t)l * 384,
                xb, xb, M, 384, 384, 0);
        }
        ln_kernel<<<M, 128, 0, stream>>>(xb, nullptr,
            ln2_g + (size_t)l * 384, ln2_b + (size_t)l * 384, hb, M);
        {
            dim3 pg(1536 / TBN, cdiv(M, TBM));
            gemm_big_kernel<<<pg, 256, 0, stream>>>(
                hb, ffn_w1 + (size_t)l * 1536 * 384, ffn_b1 + (size_t)l * 1536,
                nullptr, ffb, M, 1536, 384, 1);
        }
        {
            dim3 pg(384 / TBN, cdiv(M, TBM));
            gemm_big_kernel<<<pg, 256, 0, stream>>>(
                ffb, ffn_w2 + (size_t)l * 384 * 1536, ffn_b2 + (size_t)l * 384,
                xb, xb, M, 384, 1536, 0);
        }
    }

    // ---------- head ----------
    head_kernel<<<8, 128, 0, stream>>>(
        xb, head_ln_g, head_ln_b, head_w1, head_b1, head_w2, head_b2, (float*)d_out);
}

// Round 3
// 1591.283 us; speedup vs baseline: 7.5404x; 5.5516x over previous
//
#include <hip/hip_runtime.h>
#include <hip/hip_fp16.h>
#include <cstddef>

#define EPSV 1e-5f

typedef _Float16 f16;
typedef _Float16 f16x8 __attribute__((ext_vector_type(8)));
typedef float f32x4v __attribute__((ext_vector_type(4)));

__device__ __forceinline__ float gelu_f(float x) {
    return 0.5f * x * (1.0f + erff(x * 0.7071067811865476f));
}

// ---------------- generic f32 -> f16 convert ----------------
__global__ __launch_bounds__(256) void cvt_h_kernel(
    const float* __restrict__ in, f16* __restrict__ out, int n)
{
    for (int i = blockIdx.x * 256 + threadIdx.x; i < n; i += gridDim.x * 256)
        out[i] = (f16)in[i];
}

// ---------------- conv weight reorder: [co][ci][3][3] -> [co][tap*CI+ci] f16 ----------------
__global__ __launch_bounds__(256) void conv_w_reorder_kernel(
    const float* __restrict__ w, f16* __restrict__ out, int CO, int CI)
{
    int n = CO * CI * 9;
    for (int i = blockIdx.x * 256 + threadIdx.x; i < n; i += gridDim.x * 256) {
        int t = i % 9; int r = i / 9;
        int ci = r % CI; int co = r / CI;
        out[(size_t)co * CI * 9 + t * CI + ci] = (f16)w[i];
    }
}

// ---------------- conv1: 5x5 s2 p2, CI=1 -> CO=32, LDS input tile, NHWC f16 out ----------------
__global__ __launch_bounds__(256) void conv1_tile_kernel(
    const float* __restrict__ in, const float* __restrict__ w,
    const float* __restrict__ g, const float* __restrict__ bt,
    const float* __restrict__ mn, const float* __restrict__ vr,
    f16* __restrict__ out)
{
    __shared__ float inp[35][36];
    int bid = blockIdx.x;
    int n = bid >> 4; int tile = bid & 15;
    int ty0 = (tile >> 2) * 16, tx0 = (tile & 3) * 16;
    int t = threadIdx.x;
    const float* ip = in + (size_t)n * 16384;
    for (int e = t; e < 1225; e += 256) {
        int r = e / 35, c = e - r * 35;
        int iy = ty0 * 2 - 2 + r, ix = tx0 * 2 - 2 + c;
        inp[r][c] = ((unsigned)iy < 128u && (unsigned)ix < 128u) ? ip[iy * 128 + ix] : 0.f;
    }
    __syncthreads();
    int px = t & 15, py = t >> 4;
    float rbuf[25];
    #pragma unroll
    for (int ky = 0; ky < 5; ky++)
        #pragma unroll
        for (int kx = 0; kx < 5; kx++)
            rbuf[ky * 5 + kx] = inp[2 * py + ky][2 * px + kx];
    size_t obase = (((size_t)n * 64 + ty0 + py) * 64 + tx0 + px) * 32;
    for (int c2 = 0; c2 < 16; c2++) {
        int co0 = c2 * 2;
        float acc0 = 0.f, acc1 = 0.f;
        const float* w0 = w + co0 * 25;
        #pragma unroll
        for (int k = 0; k < 25; k++) {
            acc0 += w0[k] * rbuf[k];
            acc1 += w0[25 + k] * rbuf[k];
        }
        float inv0 = g[co0] * rsqrtf(vr[co0] + EPSV);
        float inv1 = g[co0 + 1] * rsqrtf(vr[co0 + 1] + EPSV);
        acc0 = acc0 * inv0 + (bt[co0] - mn[co0] * inv0);
        acc1 = acc1 * inv1 + (bt[co0 + 1] - mn[co0 + 1] * inv1);
        out[obase + co0] = (f16)gelu_f(acc0);
        out[obase + co0 + 1] = (f16)gelu_f(acc1);
    }
}

// ---------------- implicit-GEMM conv 3x3 s2 p1, NHWC f16, MFMA ----------------
// in [N][HI][HI][CI] f16, weights reordered [co][tap*CI+ci] f16, out [N][HO][HO][CO] f16
template<int CI, int HI, int CO>
__global__ __launch_bounds__(256) void convg_kernel(
    const f16* __restrict__ in, const f16* __restrict__ wr_,
    const float* __restrict__ g, const float* __restrict__ bt,
    const float* __restrict__ mn, const float* __restrict__ vr,
    f16* __restrict__ out)
{
    constexpr int HO = HI / 2;
    constexpr int HOB = (HO == 32) ? 5 : 4;
    constexpr int K = 9 * CI;
    __shared__ __align__(16) f16 As[64 * 40];
    __shared__ __align__(16) f16 Bs[64 * 40];
    int tid = threadIdx.x;
    int bm = blockIdx.x * 64;       // pixel tile
    int bn = blockIdx.y * 64;       // co tile
    int lrow = tid >> 2, lseg = tid & 3;
    int w = tid >> 6, lane = tid & 63;
    int wr = (w >> 1) * 32, wc = (w & 1) * 32;
    int l15 = lane & 15, l4 = lane >> 4;
    // loader pixel coords
    int gp = bm + lrow;
    int pn = gp >> (2 * HOB);
    int prem = gp & ((1 << (2 * HOB)) - 1);
    int oy = prem >> HOB, ox = prem & (HO - 1);

    f32x4v zero = {0.f, 0.f, 0.f, 0.f};
    f32x4v acc[2][2];
    acc[0][0] = zero; acc[0][1] = zero; acc[1][0] = zero; acc[1][1] = zero;

    for (int k0 = 0; k0 < K; k0 += 32) {
        int tap = k0 / CI;
        int cio = k0 - tap * CI;
        int ky = tap / 3, kx = tap - ky * 3;
        int iy = oy * 2 - 1 + ky, ix = ox * 2 - 1 + kx;
        uint4 av = make_uint4(0u, 0u, 0u, 0u);
        if ((unsigned)iy < (unsigned)HI && (unsigned)ix < (unsigned)HI)
            av = *(const uint4*)(in + (((size_t)(pn * HI + iy)) * HI + ix) * CI + cio + lseg * 8);
        *(uint4*)(&As[lrow * 40 + lseg * 8]) = av;
        uint4 bv = *(const uint4*)(wr_ + (size_t)(bn + lrow) * K + k0 + lseg * 8);
        *(uint4*)(&Bs[lrow * 40 + lseg * 8]) = bv;
        __syncthreads();
        f16x8 a0 = *(const f16x8*)(&As[(wr + l15) * 40 + l4 * 8]);
        f16x8 a1 = *(const f16x8*)(&As[(wr + 16 + l15) * 40 + l4 * 8]);
        f16x8 b0 = *(const f16x8*)(&Bs[(wc + l15) * 40 + l4 * 8]);
        f16x8 b1 = *(const f16x8*)(&Bs[(wc + 16 + l15) * 40 + l4 * 8]);
        acc[0][0] = __builtin_amdgcn_mfma_f32_16x16x32_f16(a0, b0, acc[0][0], 0, 0, 0);
        acc[0][1] = __builtin_amdgcn_mfma_f32_16x16x32_f16(a0, b1, acc[0][1], 0, 0, 0);
        acc[1][0] = __builtin_amdgcn_mfma_f32_16x16x32_f16(a1, b0, acc[1][0], 0, 0, 0);
        acc[1][1] = __builtin_amdgcn_mfma_f32_16x16x32_f16(a1, b1, acc[1][1], 0, 0, 0);
        __syncthreads();
    }
    // epilogue: BN + GELU, out NHWC (pixel-major => out[pixel*CO + co])
    float inv[2], beta[2];
    #pragma unroll
    for (int ni = 0; ni < 2; ni++) {
        int col = bn + wc + ni * 16 + l15;
        float iv = g[col] * rsqrtf(vr[col] + EPSV);
        inv[ni] = iv; beta[ni] = bt[col] - mn[col] * iv;
    }
    #pragma unroll
    for (int mi = 0; mi < 2; mi++) {
        #pragma unroll
        for (int q = 0; q < 4; q++) {
            int pixel = bm + wr + mi * 16 + l4 * 4 + q;
            #pragma unroll
            for (int ni = 0; ni < 2; ni++) {
                int col = bn + wc + ni * 16 + l15;
                float v = acc[mi][ni][q] * inv[ni] + beta[ni];
                out[(size_t)pixel * CO + col] = (f16)gelu_f(v);
            }
        }
    }
}

// ---------------- 4x4 avg pool NHWC f16: c3h [n][16][16][128] -> pooled [np][128] ----------------
__global__ __launch_bounds__(256) void poolh_kernel(
    const f16* __restrict__ in, f16* __restrict__ out, int NC)
{
    int idx = blockIdx.x * 256 + threadIdx.x;
    if (idx >= NC * 16 * 16) return;
    int cc = idx & 15; int npl = idx >> 4;
    int c0 = cc * 8;
    int n = npl >> 4; int p = npl & 15;
    int ph = p >> 2, pw = p & 3;
    const f16* base = in + (((size_t)(n * 16 + ph * 4)) * 16 + pw * 4) * 128 + c0;
    float s[8] = {};
    #pragma unroll
    for (int dy = 0; dy < 4; dy++)
        #pragma unroll
        for (int dx = 0; dx < 4; dx++) {
            f16x8 v = *(const f16x8*)(base + (dy * 16 + dx) * 128);
            #pragma unroll
            for (int u = 0; u < 8; u++) s[u] += (float)v[u];
        }
    f16* op = out + (size_t)npl * 128 + c0;
    #pragma unroll
    for (int u = 0; u < 8; u++) op[u] = (f16)(s[u] * 0.0625f);
}

// ---------------- MFMA f16 NT GEMM: C = [res +] act(A[M,K] @ B[N,K]^T + bias) ----------------
// 64x64 tile, 4 waves (2x2), each 32x32 (2x2 frags of 16x16). K%32==0, N%64==0, M guarded.
template<int OUTF16, int ACT>
__global__ __launch_bounds__(256) void gemm_h_kernel(
    const f16* __restrict__ A, const f16* __restrict__ B,
    const float* __restrict__ bias, const float* __restrict__ res,
    void* __restrict__ Cv, int M, int N, int K)
{
    __shared__ __align__(16) f16 As[64 * 40];
    __shared__ __align__(16) f16 Bs[64 * 40];
    int tid = threadIdx.x;
    int bm = blockIdx.y * 64, bn = blockIdx.x * 64;
    int lrow = tid >> 2, lseg = tid & 3;
    int w = tid >> 6, lane = tid & 63;
    int wr = (w >> 1) * 32, wc = (w & 1) * 32;
    int l15 = lane & 15, l4 = lane >> 4;
    f32x4v zero = {0.f, 0.f, 0.f, 0.f};
    f32x4v acc[2][2];
    acc[0][0] = zero; acc[0][1] = zero; acc[1][0] = zero; acc[1][1] = zero;
    int arow = bm + lrow;
    const f16* ap = A + (size_t)arow * K + lseg * 8;
    const f16* bp = B + (size_t)(bn + lrow) * K + lseg * 8;
    bool aok = (arow < M);
    for (int k0 = 0; k0 < K; k0 += 32) {
        uint4 av = make_uint4(0u, 0u, 0u, 0u);
        if (aok) av = *(const uint4*)(ap + k0);
        *(uint4*)(&As[lrow * 40 + lseg * 8]) = av;
        uint4 bv = *(const uint4*)(bp + k0);
        *(uint4*)(&Bs[lrow * 40 + lseg * 8]) = bv;
        __syncthreads();
        f16x8 a0 = *(const f16x8*)(&As[(wr + l15) * 40 + l4 * 8]);
        f16x8 a1 = *(const f16x8*)(&As[(wr + 16 + l15) * 40 + l4 * 8]);
        f16x8 b0 = *(const f16x8*)(&Bs[(wc + l15) * 40 + l4 * 8]);
        f16x8 b1 = *(const f16x8*)(&Bs[(wc + 16 + l15) * 40 + l4 * 8]);
        acc[0][0] = __builtin_amdgcn_mfma_f32_16x16x32_f16(a0, b0, acc[0][0], 0, 0, 0);
        acc[0][1] = __builtin_amdgcn_mfma_f32_16x16x32_f16(a0, b1, acc[0][1], 0, 0, 0);
        acc[1][0] = __builtin_amdgcn_mfma_f32_16x16x32_f16(a1, b0, acc[1][0], 0, 0, 0);
        acc[1][1] = __builtin_amdgcn_mfma_f32_16x16x32_f16(a1, b1, acc[1][1], 0, 0, 0);
        __syncthreads();
    }
    #pragma unroll
    for (int mi = 0; mi < 2; mi++) {
        #pragma unroll
        for (int q = 0; q < 4; q++) {
            int row = bm + wr + mi * 16 + l4 * 4 + q;
            if (row >= M) continue;
            #pragma unroll
            for (int ni = 0; ni < 2; ni++) {
                int col = bn + wc + ni * 16 + l15;
                float v = acc[mi][ni][q];
                if (bias) v += bias[col];
                if (ACT == 1) v = gelu_f(v);
                if (res) v += res[(size_t)row * N + col];
                if (OUTF16) ((f16*)Cv)[(size_t)row * N + col] = (f16)v;
                else ((float*)Cv)[(size_t)row * N + col] = v;
            }
        }
    }
}

// ---------------- tokens (b,t,p,d) f32 -> tc (b*16+p, t, d) f32 ----------------
__global__ __launch_bounds__(256) void tok2tc_kernel(
    const float* __restrict__ in, float* __restrict__ out)
{
    int idx = blockIdx.x * 256 + threadIdx.x;
    if (idx >= 8 * 32 * 16 * 384) return;
    int d = idx % 384; int t2 = idx / 384;
    int p = t2 & 15; t2 >>= 4;
    int t = t2 & 31; int b = t2 >> 5;
    out[(((size_t)(b * 16 + p) * 32 + t) * 384) + d] = in[idx];
}

// ---------------- depthwise temporal conv + bias + gelu -> f16 ----------------
__global__ __launch_bounds__(256) void dwconv_kernel(
    const float* __restrict__ in, const float* __restrict__ w,
    const float* __restrict__ bias, f16* __restrict__ out, int dil)
{
    int idx = blockIdx.x * 256 + threadIdx.x;
    if (idx >= 128 * 32 * 384) return;
    int d = idx % 384; int t = (idx / 384) & 31; int s = idx / (384 * 32);
    const float* ip = in + (size_t)s * 32 * 384 + d;
    float acc = bias[d];
    #pragma unroll
    for (int k = 0; k < 3; k++) {
        int tt = t + (k - 1) * dil;
        if ((unsigned)tt < 32u) acc += w[d * 3 + k] * ip[tt * 384];
    }
    out[idx] = (f16)gelu_f(acc);
}

// ---------------- LayerNorm over 384, f32 in -> f16 out ----------------
__global__ __launch_bounds__(128) void ln_kernel(
    const float* __restrict__ in,
    const float* __restrict__ g, const float* __restrict__ b,
    f16* __restrict__ out, int rows)
{
    int row = blockIdx.x;
    if (row >= rows) return;
    int t = threadIdx.x;
    const float* ip = in + (size_t)row * 384;
    __shared__ float red[128], red2[128];
    float x[3]; float s = 0.f, s2 = 0.f;
    #pragma unroll
    for (int j = 0; j < 3; j++) {
        float v = ip[t + 128 * j];
        x[j] = v; s += v; s2 += v * v;
    }
    red[t] = s; red2[t] = s2; __syncthreads();
    for (int off = 64; off >= 1; off >>= 1) {
        if (t < off) { red[t] += red[t + off]; red2[t] += red2[t + off]; }
        __syncthreads();
    }
    float mu = red[0] * (1.f / 384.f);
    float var = red2[0] * (1.f / 384.f) - mu * mu;
    float rs = rsqrtf(var + EPSV);
    #pragma unroll
    for (int j = 0; j < 3; j++) {
        int c = t + 128 * j;
        out[(size_t)row * 384 + c] = (f16)((x[j] - mu) * rs * g[c] + b[c]);
    }
}

// ---------------- mixer-final LN + positional add, scatter into x (f32) ----------------
__global__ __launch_bounds__(128) void build_x_kernel(
    const float* __restrict__ mix, const float* __restrict__ tc,
    const float* __restrict__ tg, const float* __restrict__ tb,
    const float* __restrict__ fpos, const float* __restrict__ ppos,
    float* __restrict__ x)
{
    int row = blockIdx.x;
    int t = row & 31; int bp = row >> 5;
    int p = bp & 15; int b = bp >> 4;
    int tid = threadIdx.x;
    const float* ip = mix + (size_t)row * 384;
    const float* ip2 = tc + (size_t)row * 384;
    __shared__ float red[128], red2[128];
    float v[3]; float s = 0.f, s2 = 0.f;
    #pragma unroll
    for (int j = 0; j < 3; j++) {
        float val = ip[tid + 128 * j] + ip2[tid + 128 * j];
        v[j] = val; s += val; s2 += val * val;
    }
    red[tid] = s; red2[tid] = s2; __syncthreads();
    for (int off = 64; off >= 1; off >>= 1) {
        if (tid < off) { red[tid] += red[tid + off]; red2[tid] += red2[tid + off]; }
        __syncthreads();
    }
    float mu = red[0] * (1.f / 384.f);
    float var = red2[0] * (1.f / 384.f) - mu * mu;
    float rs = rsqrtf(var + EPSV);
    size_t xbase = ((size_t)b * 513 + 1 + t * 16 + p) * 384;
    #pragma unroll
    for (int j = 0; j < 3; j++) {
        int c = tid + 128 * j;
        float y = (v[j] - mu) * rs * tg[c] + tb[c] + fpos[t * 384 + c] + ppos[p * 384 + c];
        x[xbase + c] = y;
    }
}

__global__ __launch_bounds__(256) void cls_kernel(
    const float* __restrict__ ct, const float* __restrict__ cp, float* __restrict__ x)
{
    int idx = blockIdx.x * 256 + threadIdx.x;
    if (idx >= 8 * 384) return;
    int c = idx % 384; int b = idx / 384;
    x[(size_t)b * 513 * 384 + c] = ct[c] + cp[c];
}

// ---------------- flash attention (fp32 compute), qkv f32 in, f16 out ----------------
__global__ __launch_bounds__(256) void fattn_kernel(
    const float* __restrict__ qkv, f16* __restrict__ out)
{
    __shared__ __align__(16) float Qs[64][65];
    __shared__ __align__(16) float KVs[64][65];
    __shared__ __align__(16) float Ps[64][65];
    __shared__ float red[64][16];

    int qt = blockIdx.x;
    int bh = blockIdx.y; int h = bh % 6; int b = bh / 6;
    int tid = threadIdx.x;
    int tx = tid & 15, ty = tid >> 4;
    int lr = tid >> 2, lc = (tid & 3) * 16;
    int q0 = qt * 64;
    const size_t RS = 1152;
    const float* base = qkv + (size_t)(b * 513) * RS + h * 64;

    {
        float rq[16];
        int qi = q0 + lr;
        if (qi < 513) {
            const float* p = base + (size_t)qi * RS + lc;
            *reinterpret_cast<float4*>(rq + 0)  = *reinterpret_cast<const float4*>(p + 0);
            *reinterpret_cast<float4*>(rq + 4)  = *reinterpret_cast<const float4*>(p + 4);
            *reinterpret_cast<float4*>(rq + 8)  = *reinterpret_cast<const float4*>(p + 8);
            *reinterpret_cast<float4*>(rq + 12) = *reinterpret_cast<const float4*>(p + 12);
        } else {
            #pragma unroll
            for (int u = 0; u < 16; u++) rq[u] = 0.f;
        }
        #pragma unroll
        for (int u = 0; u < 16; u++) Qs[lc + u][lr] = rq[u];
    }

    float O[4][4] = {};
    float m[4], l[4];
    #pragma unroll
    for (int i = 0; i < 4; i++) { m[i] = -INFINITY; l[i] = 0.f; }

    int jt0 = 0;
    if (qt > 0) {
        int fmin = (q0 - 1) >> 4;
        jt0 = (fmin * 16 + 1) >> 6;
    }

    for (int jt = jt0; jt < 9; jt++) {
        int j0 = jt * 64;
        __syncthreads();
        {
            float rk[16];
            int j = j0 + lr;
            if (j < 513) {
                const float* p = base + (size_t)j * RS + 384 + lc;
                *reinterpret_cast<float4*>(rk + 0)  = *reinterpret_cast<const float4*>(p + 0);
                *reinterpret_cast<float4*>(rk + 4)  = *reinterpret_cast<const float4*>(p + 4);
                *reinterpret_cast<float4*>(rk + 8)  = *reinterpret_cast<const float4*>(p + 8);
                *reinterpret_cast<float4*>(rk + 12) = *reinterpret_cast<const float4*>(p + 12);
            } else {
                #pragma unroll
                for (int u = 0; u < 16; u++) rk[u] = 0.f;
            }
            #pragma unroll
            for (int u = 0; u < 16; u++) KVs[lc + u][lr] = rk[u];
        }
        float rv[16];
        {
            int j = j0 + lr;
            if (j < 513) {
                const float* p = base + (size_t)j * RS + 768 + lc;
                *reinterpret_cast<float4*>(rv + 0)  = *reinterpret_cast<const float4*>(p + 0);
                *reinterpret_cast<float4*>(rv + 4)  = *reinterpret_cast<const float4*>(p + 4);
                *reinterpret_cast<float4*>(rv + 8)  = *reinterpret_cast<const float4*>(p + 8);
                *reinterpret_cast<float4*>(rv + 12) = *reinterpret_cast<const float4*>(p + 12);
            } else {
                #pragma unroll
                for (int u = 0; u < 16; u++) rv[u] = 0.f;
            }
        }
        __syncthreads();

        float s[4][4] = {};
        #pragma unroll 8
        for (int d = 0; d < 64; d++) {
            float4 qv = *reinterpret_cast<const float4*>(&Qs[d][ty * 4]);
            float4 kv = *reinterpret_cast<const float4*>(&KVs[d][tx * 4]);
            float qa[4] = {qv.x, qv.y, qv.z, qv.w};
            float ka[4] = {kv.x, kv.y, kv.z, kv.w};
            #pragma unroll
            for (int i = 0; i < 4; i++)
                #pragma unroll
                for (int jj = 0; jj < 4; jj++)
                    s[i][jj] += qa[i] * ka[jj];
        }
        #pragma unroll
        for (int i = 0; i < 4; i++) {
            int qi = q0 + ty * 4 + i;
            int fi = (qi == 0) ? -1 : ((qi - 1) >> 4);
            #pragma unroll
            for (int jj = 0; jj < 4; jj++) {
                int j = j0 + tx * 4 + jj;
                bool valid = (qi < 513) && (j < 513) &&
                             !((qi != 0) && ((j == 0) || (((j - 1) >> 4) < fi)));
                s[i][jj] = valid ? s[i][jj] * 0.125f : -INFINITY;
            }
        }
        #pragma unroll
        for (int i = 0; i < 4; i++) {
            float tm = fmaxf(fmaxf(s[i][0], s[i][1]), fmaxf(s[i][2], s[i][3]));
            red[ty * 4 + i][tx] = tm;
        }
        __syncthreads();
        float mnew[4], alpha[4], lpart[4];
        #pragma unroll
        for (int i = 0; i < 4; i++) {
            int r = ty * 4 + i;
            float mt = -INFINITY;
            #pragma unroll
            for (int t = 0; t < 16; t++) mt = fmaxf(mt, red[r][t]);
            mnew[i] = fmaxf(m[i], mt);
            alpha[i] = (m[i] == -INFINITY) ? 0.f : __expf(m[i] - mnew[i]);
            float lp = 0.f;
            #pragma unroll
            for (int jj = 0; jj < 4; jj++) {
                float p = (s[i][jj] == -INFINITY) ? 0.f : __expf(s[i][jj] - mnew[i]);
                s[i][jj] = p; lp += p;
            }
            lpart[i] = lp;
        }
        __syncthreads();
        #pragma unroll
        for (int i = 0; i < 4; i++) {
            red[ty * 4 + i][tx] = lpart[i];
            #pragma unroll
            for (int jj = 0; jj < 4; jj++)
                Ps[tx * 4 + jj][ty * 4 + i] = s[i][jj];
        }
        {
            #pragma unroll
            for (int u = 0; u < 4; u++)
                *reinterpret_cast<float4*>(&KVs[lr][lc + u * 4]) = *reinterpret_cast<float4*>(rv + u * 4);
        }
        __syncthreads();
        #pragma unroll
        for (int i = 0; i < 4; i++) {
            int r = ty * 4 + i;
            float lt = 0.f;
            #pragma unroll
            for (int t = 0; t < 16; t++) lt += red[r][t];
            l[i] = alpha[i] * l[i] + lt;
            m[i] = mnew[i];
        }
        #pragma unroll
        for (int i = 0; i < 4; i++)
            #pragma unroll
            for (int dd = 0; dd < 4; dd++)
                O[i][dd] *= alpha[i];
        #pragma unroll 8
        for (int j = 0; j < 64; j++) {
            float4 pv = *reinterpret_cast<const float4*>(&Ps[j][ty * 4]);
            float4 vv = *reinterpret_cast<const float4*>(&KVs[j][tx * 4]);
            float pa[4] = {pv.x, pv.y, pv.z, pv.w};
            float va[4] = {vv.x, vv.y, vv.z, vv.w};
            #pragma unroll
            for (int i = 0; i < 4; i++)
                #pragma unroll
                for (int dd = 0; dd < 4; dd++)
                    O[i][dd] += pa[i] * va[dd];
        }
    }

    #pragma unroll
    for (int i = 0; i < 4; i++) {
        int qi = q0 + ty * 4 + i;
        if (qi >= 513) continue;
        float rl = 1.0f / l[i];
        f16* op = out + ((size_t)(b * 513 + qi)) * 384 + h * 64 + tx * 4;
        #pragma unroll
        for (int dd = 0; dd < 4; dd++) op[dd] = (f16)(O[i][dd] * rl);
    }
}

// ---------------- head: LN + MLP(384->384 gelu ->2) + sigmoid ----------------
__global__ __launch_bounds__(128) void head_kernel(
    const float* __restrict__ x, const float* __restrict__ lg, const float* __restrict__ lb,
    const float* __restrict__ w1, const float* __restrict__ b1,
    const float* __restrict__ w2, const float* __restrict__ b2,
    float* __restrict__ out)
{
    int b = blockIdx.x; int t = threadIdx.x;
    __shared__ float hs[384], h1[384];
    __shared__ float red[128], red2[128];
    const float* xp = x + (size_t)b * 513 * 384;
    float v[3]; float s = 0.f, s2 = 0.f;
    #pragma unroll
    for (int j = 0; j < 3; j++) {
        float val = xp[t + 128 * j];
        v[j] = val; s += val; s2 += val * val;
    }
    red[t] = s; red2[t] = s2; __syncthreads();
    for (int off = 64; off >= 1; off >>= 1) {
        if (t < off) { red[t] += red[t + off]; red2[t] += red2[t + off]; }
        __syncthreads();
    }
    float mu = red[0] * (1.f / 384.f);
    float var = red2[0] * (1.f / 384.f) - mu * mu;
    float rs = rsqrtf(var + EPSV);
    #pragma unroll
    for (int j = 0; j < 3; j++) {
        int c = t + 128 * j;
        hs[c] = (v[j] - mu) * rs * lg[c] + lb[c];
    }
    __syncthreads();
    #pragma unroll
    for (int j = 0; j < 3; j++) {
        int o = t + 128 * j;
        const float* wr = w1 + (size_t)o * 384;
        float acc = b1[o];
        for (int c = 0; c < 384; c++) acc += wr[c] * hs[c];
        h1[o] = gelu_f(acc);
    }
    __syncthreads();
    if (t < 2) {
        const float* wr = w2 + (size_t)t * 384;
        float acc = b2[t];
        for (int c = 0; c < 384; c++) acc += wr[c] * h1[c];
        out[b * 2 + t] = 1.f / (1.f + expf(-acc));
    }
}

static inline int cdiv(int a, int b) { return (a + b - 1) / b; }

extern "C" void kernel_launch(void* const* d_in, const int* in_sizes, int n_in,
                              void* d_out, int out_size, void* d_ws, size_t ws_size,
                              hipStream_t stream)
{
    const float* frames  = (const float*)d_in[0];
    const float* conv1_w = (const float*)d_in[1];
    const float* bn1_g = (const float*)d_in[2]; const float* bn1_b = (const float*)d_in[3];
    const float* bn1_m = (const float*)d_in[4]; const float* bn1_v = (const float*)d_in[5];
    const float* conv2_w = (const float*)d_in[6];
    const float* bn2_g = (const float*)d_in[7]; const float* bn2_b = (const float*)d_in[8];
    const float* bn2_m = (const float*)d_in[9]; const float* bn2_v = (const float*)d_in[10];
    const float* conv3_w = (const float*)d_in[11];
    const float* bn3_g = (const float*)d_in[12]; const float* bn3_b = (const float*)d_in[13];
    const float* bn3_m = (const float*)d_in[14]; const float* bn3_v = (const float*)d_in[15];
    const float* proj_w = (const float*)d_in[16];
    const float* dw_w = (const float*)d_in[17]; const float* dw_b = (const float*)d_in[18];
    const float* pw_w = (const float*)d_in[19]; const float* pw_b = (const float*)d_in[20];
    const float* tnorm_g = (const float*)d_in[21]; const float* tnorm_b = (const float*)d_in[22];
    const float* frame_pos = (const float*)d_in[23];
    const float* patch_pos = (const float*)d_in[24];
    const float* cls_token = (const float*)d_in[25];
    const float* cls_pos = (const float*)d_in[26];
    const float* qkv_w = (const float*)d_in[27]; const float* qkv_b = (const float*)d_in[28];
    const float* out_w = (const float*)d_in[29]; const float* out_b = (const float*)d_in[30];
    const float* ln1_g = (const float*)d_in[31]; const float* ln1_b = (const float*)d_in[32];
    const float* ln2_g = (const float*)d_in[33]; const float* ln2_b = (const float*)d_in[34];
    const float* ffn_w1 = (const float*)d_in[35]; const float* ffn_b1 = (const float*)d_in[36];
    const float* ffn_w2 = (const float*)d_in[37]; const float* ffn_b2 = (const float*)d_in[38];
    const float* head_ln_g = (const float*)d_in[39]; const float* head_ln_b = (const float*)d_in[40];
    const float* head_w1 = (const float*)d_in[41]; const float* head_b1 = (const float*)d_in[42];
    const float* head_w2 = (const float*)d_in[43]; const float* head_b2 = (const float*)d_in[44];
    (void)in_sizes; (void)n_in; (void)out_size; (void)ws_size;

    char* base = (char*)d_ws;
    size_t off = 0;
    auto alloc = [&](size_t bytes) { void* p = base + off; off = (off + bytes + 255) & ~(size_t)255; return p; };

    // f16 weights
    f16* projw16 = (f16*)alloc(384 * 128 * 2);
    f16* pw16    = (f16*)alloc((size_t)2 * 384 * 384 * 2);
    f16* qkvw16  = (f16*)alloc((size_t)6 * 1152 * 384 * 2);
    f16* outw16  = (f16*)alloc((size_t)6 * 384 * 384 * 2);
    f16* f1w16   = (f16*)alloc((size_t)6 * 1536 * 384 * 2);
    f16* f2w16   = (f16*)alloc((size_t)6 * 384 * 1536 * 2);
    f16* c2w16   = (f16*)alloc((size_t)64 * 288 * 2);
    f16* c3w16   = (f16*)alloc((size_t)128 * 576 * 2);
    // activations
    float* tokens = (float*)alloc((size_t)4096 * 384 * 4);
    f16* pooled   = (f16*)alloc((size_t)4096 * 128 * 2);
    f16* c1h = (f16*)alloc((size_t)64 * 64 * 64 * 32 * 2);
    f16* c2h = (f16*)alloc((size_t)64 * 32 * 32 * 64 * 2);
    f16* c3h = (f16*)alloc((size_t)64 * 16 * 16 * 128 * 2);
    float* tc = (float*)alloc((size_t)4096 * 384 * 4);
    float* mA = (float*)alloc((size_t)4096 * 384 * 4);
    float* mB = (float*)alloc((size_t)4096 * 384 * 4);
    f16*   mh = (f16*)alloc((size_t)4096 * 384 * 2);
    float* xb   = (float*)alloc((size_t)8 * 513 * 384 * 4);
    f16*   hb   = (f16*)alloc((size_t)8 * 513 * 384 * 2);
    float* qkvb = (float*)alloc((size_t)8 * 513 * 1152 * 4);
    f16*   ob   = (f16*)alloc((size_t)8 * 513 * 384 * 2);
    f16*   ffb  = (f16*)alloc((size_t)8 * 513 * 1536 * 2);

    // ---------- weight conversion ----------
    auto cvt = [&](const float* src, f16* dst, int n) {
        cvt_h_kernel<<<min(cdiv(n, 256), 2048), 256, 0, stream>>>(src, dst, n);
    };
    cvt(proj_w, projw16, 384 * 128);
    cvt(pw_w, pw16, 2 * 384 * 384);
    cvt(qkv_w, qkvw16, 6 * 1152 * 384);
    cvt(out_w, outw16, 6 * 384 * 384);
    cvt(ffn_w1, f1w16, 6 * 1536 * 384);
    cvt(ffn_w2, f2w16, 6 * 384 * 1536);
    conv_w_reorder_kernel<<<cdiv(64 * 288, 256), 256, 0, stream>>>(conv2_w, c2w16, 64, 32);
    conv_w_reorder_kernel<<<cdiv(128 * 576, 256), 256, 0, stream>>>(conv3_w, c3w16, 128, 64);

    // ---------- conv stem, 4 chunks of 64 frames ----------
    for (int ch = 0; ch < 4; ch++) {
        const float* fch = frames + (size_t)ch * 64 * 16384;
        conv1_tile_kernel<<<64 * 16, 256, 0, stream>>>(
            fch, conv1_w, bn1_g, bn1_b, bn1_m, bn1_v, c1h);
        convg_kernel<32, 64, 64><<<dim3(1024, 1), 256, 0, stream>>>(
            c1h, c2w16, bn2_g, bn2_b, bn2_m, bn2_v, c2h);
        convg_kernel<64, 32, 128><<<dim3(256, 2), 256, 0, stream>>>(
            c2h, c3w16, bn3_g, bn3_b, bn3_m, bn3_v, c3h);
        poolh_kernel<<<64, 256, 0, stream>>>(c3h, pooled + (size_t)ch * 1024 * 128, 64);
    }
    // proj: tokens[4096,384] = pooled[4096,128] @ projw16^T
    gemm_h_kernel<0, 0><<<dim3(6, 64), 256, 0, stream>>>(
        pooled, projw16, nullptr, nullptr, tokens, 4096, 384, 128);

    // ---------- temporal mixer ----------
    tok2tc_kernel<<<cdiv(8 * 32 * 16 * 384, 256), 256, 0, stream>>>(tokens, tc);
    hipMemcpyAsync(mA, tc, (size_t)4096 * 384 * sizeof(float), hipMemcpyDeviceToDevice, stream);
    float* cur = mA; float* alt = mB;
    for (int it = 0; it < 2; it++) {
        int dil = (it == 0) ? 1 : 2;
        dwconv_kernel<<<cdiv(128 * 32 * 384, 256), 256, 0, stream>>>(
            cur, dw_w + (size_t)it * 384 * 3, dw_b + (size_t)it * 384, mh, dil);
        gemm_h_kernel<0, 0><<<dim3(6, 64), 256, 0, stream>>>(
            mh, pw16 + (size_t)it * 384 * 384, pw_b + (size_t)it * 384, cur,
            alt, 4096, 384, 384);
        float* tmp = cur; cur = alt; alt = tmp;
    }

    // ---------- build transformer input x ----------
    build_x_kernel<<<128 * 32, 128, 0, stream>>>(
        cur, tc, tnorm_g, tnorm_b, frame_pos, patch_pos, xb);
    cls_kernel<<<cdiv(8 * 384, 256), 256, 0, stream>>>(cls_token, cls_pos, xb);

    // ---------- transformer ----------
    const int M = 8 * 513;   // 4104
    const int MG = cdiv(M, 64);   // 65
    for (int l = 0; l < 6; l++) {
        ln_kernel<<<M, 128, 0, stream>>>(xb,
            ln1_g + (size_t)l * 384, ln1_b + (size_t)l * 384, hb, M);
        gemm_h_kernel<0, 0><<<dim3(18, MG), 256, 0, stream>>>(
            hb, qkvw16 + (size_t)l * 1152 * 384, qkv_b + (size_t)l * 1152,
            nullptr, qkvb, M, 1152, 384);
        {
            dim3 ag(9, 48);
            fattn_kernel<<<ag, 256, 0, stream>>>(qkvb, ob);
        }
        gemm_h_kernel<0, 0><<<dim3(6, MG), 256, 0, stream>>>(
            ob, outw16 + (size_t)l * 384 * 384, out_b + (size_t)l * 384,
            xb, xb, M, 384, 384);
        ln_kernel<<<M, 128, 0, stream>>>(xb,
            ln2_g + (size_t)l * 384, ln2_b + (size_t)l * 384, hb, M);
        gemm_h_kernel<1, 1><<<dim3(24, MG), 256, 0, stream>>>(
            hb, f1w16 + (size_t)l * 1536 * 384, ffn_b1 + (size_t)l * 1536,
            nullptr, ffb, M, 1536, 384);
        gemm_h_kernel<0, 0><<<dim3(6, MG), 256, 0, stream>>>(
            ffb, f2w16 + (size_t)l * 384 * 1536, ffn_b2 + (size_t)l * 384,
            xb, xb, M, 384, 1536);
    }

    // ---------- head ----------
    head_kernel<<<8, 128, 0, stream>>>(
        xb, head_ln_g, head_ln_b, head_w1, head_b1, head_w2, head_b2, (float*)d_out);
}

// Round 4
// 1275.193 us; speedup vs baseline: 9.4095x; 1.2479x over previous
//
#include <hip/hip_runtime.h>
#include <hip/hip_fp16.h>
#include <cstddef>

#define EPSV 1e-5f

typedef _Float16 f16;
typedef _Float16 f16x8 __attribute__((ext_vector_type(8)));
typedef float f32x4v __attribute__((ext_vector_type(4)));

__device__ __forceinline__ float gelu_f(float x) {
    return 0.5f * x * (1.0f + erff(x * 0.7071067811865476f));
}

// ---------------- generic f32 -> f16 convert ----------------
__global__ __launch_bounds__(256) void cvt_h_kernel(
    const float* __restrict__ in, f16* __restrict__ out, int n)
{
    for (int i = blockIdx.x * 256 + threadIdx.x; i < n; i += gridDim.x * 256)
        out[i] = (f16)in[i];
}

// ---------------- conv weight reorder: [co][ci][3][3] -> [co][tap*CI+ci] f16 ----------------
__global__ __launch_bounds__(256) void conv_w_reorder_kernel(
    const float* __restrict__ w, f16* __restrict__ out, int CO, int CI)
{
    int n = CO * CI * 9;
    for (int i = blockIdx.x * 256 + threadIdx.x; i < n; i += gridDim.x * 256) {
        int t = i % 9; int r = i / 9;
        int ci = r % CI; int co = r / CI;
        out[(size_t)co * CI * 9 + t * CI + ci] = (f16)w[i];
    }
}

// ---------------- conv1: 5x5 s2 p2, CI=1 -> CO=32, LDS input tile, NHWC f16 out ----------------
__global__ __launch_bounds__(256) void conv1_tile_kernel(
    const float* __restrict__ in, const float* __restrict__ w,
    const float* __restrict__ g, const float* __restrict__ bt,
    const float* __restrict__ mn, const float* __restrict__ vr,
    f16* __restrict__ out)
{
    __shared__ float inp[35][36];
    int bid = blockIdx.x;
    int n = bid >> 4; int tile = bid & 15;
    int ty0 = (tile >> 2) * 16, tx0 = (tile & 3) * 16;
    int t = threadIdx.x;
    const float* ip = in + (size_t)n * 16384;
    for (int e = t; e < 1225; e += 256) {
        int r = e / 35, c = e - r * 35;
        int iy = ty0 * 2 - 2 + r, ix = tx0 * 2 - 2 + c;
        inp[r][c] = ((unsigned)iy < 128u && (unsigned)ix < 128u) ? ip[iy * 128 + ix] : 0.f;
    }
    __syncthreads();
    int px = t & 15, py = t >> 4;
    float rbuf[25];
    #pragma unroll
    for (int ky = 0; ky < 5; ky++)
        #pragma unroll
        for (int kx = 0; kx < 5; kx++)
            rbuf[ky * 5 + kx] = inp[2 * py + ky][2 * px + kx];
    size_t obase = (((size_t)n * 64 + ty0 + py) * 64 + tx0 + px) * 32;
    for (int c2 = 0; c2 < 16; c2++) {
        int co0 = c2 * 2;
        float acc0 = 0.f, acc1 = 0.f;
        const float* w0 = w + co0 * 25;
        #pragma unroll
        for (int k = 0; k < 25; k++) {
            acc0 += w0[k] * rbuf[k];
            acc1 += w0[25 + k] * rbuf[k];
        }
        float inv0 = g[co0] * rsqrtf(vr[co0] + EPSV);
        float inv1 = g[co0 + 1] * rsqrtf(vr[co0 + 1] + EPSV);
        acc0 = acc0 * inv0 + (bt[co0] - mn[co0] * inv0);
        acc1 = acc1 * inv1 + (bt[co0 + 1] - mn[co0 + 1] * inv1);
        out[obase + co0] = (f16)gelu_f(acc0);
        out[obase + co0 + 1] = (f16)gelu_f(acc1);
    }
}

// ---------------- implicit-GEMM conv 3x3 s2 p1, NHWC f16, MFMA ----------------
template<int CI, int HI, int CO>
__global__ __launch_bounds__(256) void convg_kernel(
    const f16* __restrict__ in, const f16* __restrict__ wr_,
    const float* __restrict__ g, const float* __restrict__ bt,
    const float* __restrict__ mn, const float* __restrict__ vr,
    f16* __restrict__ out)
{
    constexpr int HO = HI / 2;
    constexpr int HOB = (HO == 32) ? 5 : 4;
    constexpr int K = 9 * CI;
    __shared__ __align__(16) f16 As[64 * 40];
    __shared__ __align__(16) f16 Bs[64 * 40];
    int tid = threadIdx.x;
    int bm = blockIdx.x * 64;
    int bn = blockIdx.y * 64;
    int lrow = tid >> 2, lseg = tid & 3;
    int w = tid >> 6, lane = tid & 63;
    int wr = (w >> 1) * 32, wc = (w & 1) * 32;
    int l15 = lane & 15, l4 = lane >> 4;
    int gp = bm + lrow;
    int pn = gp >> (2 * HOB);
    int prem = gp & ((1 << (2 * HOB)) - 1);
    int oy = prem >> HOB, ox = prem & (HO - 1);

    f32x4v zero = {0.f, 0.f, 0.f, 0.f};
    f32x4v acc[2][2];
    acc[0][0] = zero; acc[0][1] = zero; acc[1][0] = zero; acc[1][1] = zero;

    for (int k0 = 0; k0 < K; k0 += 32) {
        int tap = k0 / CI;
        int cio = k0 - tap * CI;
        int ky = tap / 3, kx = tap - ky * 3;
        int iy = oy * 2 - 1 + ky, ix = ox * 2 - 1 + kx;
        uint4 av = make_uint4(0u, 0u, 0u, 0u);
        if ((unsigned)iy < (unsigned)HI && (unsigned)ix < (unsigned)HI)
            av = *(const uint4*)(in + (((size_t)(pn * HI + iy)) * HI + ix) * CI + cio + lseg * 8);
        *(uint4*)(&As[lrow * 40 + lseg * 8]) = av;
        uint4 bv = *(const uint4*)(wr_ + (size_t)(bn + lrow) * K + k0 + lseg * 8);
        *(uint4*)(&Bs[lrow * 40 + lseg * 8]) = bv;
        __syncthreads();
        f16x8 a0 = *(const f16x8*)(&As[(wr + l15) * 40 + l4 * 8]);
        f16x8 a1 = *(const f16x8*)(&As[(wr + 16 + l15) * 40 + l4 * 8]);
        f16x8 b0 = *(const f16x8*)(&Bs[(wc + l15) * 40 + l4 * 8]);
        f16x8 b1 = *(const f16x8*)(&Bs[(wc + 16 + l15) * 40 + l4 * 8]);
        acc[0][0] = __builtin_amdgcn_mfma_f32_16x16x32_f16(a0, b0, acc[0][0], 0, 0, 0);
        acc[0][1] = __builtin_amdgcn_mfma_f32_16x16x32_f16(a0, b1, acc[0][1], 0, 0, 0);
        acc[1][0] = __builtin_amdgcn_mfma_f32_16x16x32_f16(a1, b0, acc[1][0], 0, 0, 0);
        acc[1][1] = __builtin_amdgcn_mfma_f32_16x16x32_f16(a1, b1, acc[1][1], 0, 0, 0);
        __syncthreads();
    }
    float inv[2], beta[2];
    #pragma unroll
    for (int ni = 0; ni < 2; ni++) {
        int col = bn + wc + ni * 16 + l15;
        float iv = g[col] * rsqrtf(vr[col] + EPSV);
        inv[ni] = iv; beta[ni] = bt[col] - mn[col] * iv;
    }
    #pragma unroll
    for (int mi = 0; mi < 2; mi++) {
        #pragma unroll
        for (int q = 0; q < 4; q++) {
            int pixel = bm + wr + mi * 16 + l4 * 4 + q;
            #pragma unroll
            for (int ni = 0; ni < 2; ni++) {
                int col = bn + wc + ni * 16 + l15;
                float v = acc[mi][ni][q] * inv[ni] + beta[ni];
                out[(size_t)pixel * CO + col] = (f16)gelu_f(v);
            }
        }
    }
}

// ---------------- 4x4 avg pool NHWC f16 ----------------
__global__ __launch_bounds__(256) void poolh_kernel(
    const f16* __restrict__ in, f16* __restrict__ out, int NC)
{
    int idx = blockIdx.x * 256 + threadIdx.x;
    if (idx >= NC * 16 * 16) return;
    int cc = idx & 15; int npl = idx >> 4;
    int c0 = cc * 8;
    int n = npl >> 4; int p = npl & 15;
    int ph = p >> 2, pw = p & 3;
    const f16* base = in + (((size_t)(n * 16 + ph * 4)) * 16 + pw * 4) * 128 + c0;
    float s[8] = {};
    #pragma unroll
    for (int dy = 0; dy < 4; dy++)
        #pragma unroll
        for (int dx = 0; dx < 4; dx++) {
            f16x8 v = *(const f16x8*)(base + (dy * 16 + dx) * 128);
            #pragma unroll
            for (int u = 0; u < 8; u++) s[u] += (float)v[u];
        }
    f16* op = out + (size_t)npl * 128 + c0;
    #pragma unroll
    for (int u = 0; u < 8; u++) op[u] = (f16)(s[u] * 0.0625f);
}

// ---------------- MFMA f16 NT GEMM ----------------
template<int OUTF16, int ACT>
__global__ __launch_bounds__(256) void gemm_h_kernel(
    const f16* __restrict__ A, const f16* __restrict__ B,
    const float* __restrict__ bias, const float* __restrict__ res,
    void* __restrict__ Cv, int M, int N, int K)
{
    __shared__ __align__(16) f16 As[64 * 40];
    __shared__ __align__(16) f16 Bs[64 * 40];
    int tid = threadIdx.x;
    int bm = blockIdx.y * 64, bn = blockIdx.x * 64;
    int lrow = tid >> 2, lseg = tid & 3;
    int w = tid >> 6, lane = tid & 63;
    int wr = (w >> 1) * 32, wc = (w & 1) * 32;
    int l15 = lane & 15, l4 = lane >> 4;
    f32x4v zero = {0.f, 0.f, 0.f, 0.f};
    f32x4v acc[2][2];
    acc[0][0] = zero; acc[0][1] = zero; acc[1][0] = zero; acc[1][1] = zero;
    int arow = bm + lrow;
    const f16* ap = A + (size_t)arow * K + lseg * 8;
    const f16* bp = B + (size_t)(bn + lrow) * K + lseg * 8;
    bool aok = (arow < M);
    for (int k0 = 0; k0 < K; k0 += 32) {
        uint4 av = make_uint4(0u, 0u, 0u, 0u);
        if (aok) av = *(const uint4*)(ap + k0);
        *(uint4*)(&As[lrow * 40 + lseg * 8]) = av;
        uint4 bv = *(const uint4*)(bp + k0);
        *(uint4*)(&Bs[lrow * 40 + lseg * 8]) = bv;
        __syncthreads();
        f16x8 a0 = *(const f16x8*)(&As[(wr + l15) * 40 + l4 * 8]);
        f16x8 a1 = *(const f16x8*)(&As[(wr + 16 + l15) * 40 + l4 * 8]);
        f16x8 b0 = *(const f16x8*)(&Bs[(wc + l15) * 40 + l4 * 8]);
        f16x8 b1 = *(const f16x8*)(&Bs[(wc + 16 + l15) * 40 + l4 * 8]);
        acc[0][0] = __builtin_amdgcn_mfma_f32_16x16x32_f16(a0, b0, acc[0][0], 0, 0, 0);
        acc[0][1] = __builtin_amdgcn_mfma_f32_16x16x32_f16(a0, b1, acc[0][1], 0, 0, 0);
        acc[1][0] = __builtin_amdgcn_mfma_f32_16x16x32_f16(a1, b0, acc[1][0], 0, 0, 0);
        acc[1][1] = __builtin_amdgcn_mfma_f32_16x16x32_f16(a1, b1, acc[1][1], 0, 0, 0);
        __syncthreads();
    }
    #pragma unroll
    for (int mi = 0; mi < 2; mi++) {
        #pragma unroll
        for (int q = 0; q < 4; q++) {
            int row = bm + wr + mi * 16 + l4 * 4 + q;
            if (row >= M) continue;
            #pragma unroll
            for (int ni = 0; ni < 2; ni++) {
                int col = bn + wc + ni * 16 + l15;
                float v = acc[mi][ni][q];
                if (bias) v += bias[col];
                if (ACT == 1) v = gelu_f(v);
                if (res) v += res[(size_t)row * N + col];
                if (OUTF16) ((f16*)Cv)[(size_t)row * N + col] = (f16)v;
                else ((float*)Cv)[(size_t)row * N + col] = v;
            }
        }
    }
}

// ---------------- tokens (b,t,p,d) f32 -> tc (b*16+p, t, d) f32 ----------------
__global__ __launch_bounds__(256) void tok2tc_kernel(
    const float* __restrict__ in, float* __restrict__ out)
{
    int idx = blockIdx.x * 256 + threadIdx.x;
    if (idx >= 8 * 32 * 16 * 384) return;
    int d = idx % 384; int t2 = idx / 384;
    int p = t2 & 15; t2 >>= 4;
    int t = t2 & 31; int b = t2 >> 5;
    out[(((size_t)(b * 16 + p) * 32 + t) * 384) + d] = in[idx];
}

// ---------------- depthwise temporal conv + bias + gelu -> f16 ----------------
__global__ __launch_bounds__(256) void dwconv_kernel(
    const float* __restrict__ in, const float* __restrict__ w,
    const float* __restrict__ bias, f16* __restrict__ out, int dil)
{
    int idx = blockIdx.x * 256 + threadIdx.x;
    if (idx >= 128 * 32 * 384) return;
    int d = idx % 384; int t = (idx / 384) & 31; int s = idx / (384 * 32);
    const float* ip = in + (size_t)s * 32 * 384 + d;
    float acc = bias[d];
    #pragma unroll
    for (int k = 0; k < 3; k++) {
        int tt = t + (k - 1) * dil;
        if ((unsigned)tt < 32u) acc += w[d * 3 + k] * ip[tt * 384];
    }
    out[idx] = (f16)gelu_f(acc);
}

// ---------------- LayerNorm over 384, f32 in -> f16 out ----------------
__global__ __launch_bounds__(128) void ln_kernel(
    const float* __restrict__ in,
    const float* __restrict__ g, const float* __restrict__ b,
    f16* __restrict__ out, int rows)
{
    int row = blockIdx.x;
    if (row >= rows) return;
    int t = threadIdx.x;
    const float* ip = in + (size_t)row * 384;
    __shared__ float red[128], red2[128];
    float x[3]; float s = 0.f, s2 = 0.f;
    #pragma unroll
    for (int j = 0; j < 3; j++) {
        float v = ip[t + 128 * j];
        x[j] = v; s += v; s2 += v * v;
    }
    red[t] = s; red2[t] = s2; __syncthreads();
    for (int off = 64; off >= 1; off >>= 1) {
        if (t < off) { red[t] += red[t + off]; red2[t] += red2[t + off]; }
        __syncthreads();
    }
    float mu = red[0] * (1.f / 384.f);
    float var = red2[0] * (1.f / 384.f) - mu * mu;
    float rs = rsqrtf(var + EPSV);
    #pragma unroll
    for (int j = 0; j < 3; j++) {
        int c = t + 128 * j;
        out[(size_t)row * 384 + c] = (f16)((x[j] - mu) * rs * g[c] + b[c]);
    }
}

// ---------------- mixer-final LN + positional add, scatter into x (f32) ----------------
__global__ __launch_bounds__(128) void build_x_kernel(
    const float* __restrict__ mix, const float* __restrict__ tc,
    const float* __restrict__ tg, const float* __restrict__ tb,
    const float* __restrict__ fpos, const float* __restrict__ ppos,
    float* __restrict__ x)
{
    int row = blockIdx.x;
    int t = row & 31; int bp = row >> 5;
    int p = bp & 15; int b = bp >> 4;
    int tid = threadIdx.x;
    const float* ip = mix + (size_t)row * 384;
    const float* ip2 = tc + (size_t)row * 384;
    __shared__ float red[128], red2[128];
    float v[3]; float s = 0.f, s2 = 0.f;
    #pragma unroll
    for (int j = 0; j < 3; j++) {
        float val = ip[tid + 128 * j] + ip2[tid + 128 * j];
        v[j] = val; s += val; s2 += val * val;
    }
    red[tid] = s; red2[tid] = s2; __syncthreads();
    for (int off = 64; off >= 1; off >>= 1) {
        if (tid < off) { red[tid] += red[tid + off]; red2[tid] += red2[tid + off]; }
        __syncthreads();
    }
    float mu = red[0] * (1.f / 384.f);
    float var = red2[0] * (1.f / 384.f) - mu * mu;
    float rs = rsqrtf(var + EPSV);
    size_t xbase = ((size_t)b * 513 + 1 + t * 16 + p) * 384;
    #pragma unroll
    for (int j = 0; j < 3; j++) {
        int c = tid + 128 * j;
        float y = (v[j] - mu) * rs * tg[c] + tb[c] + fpos[t * 384 + c] + ppos[p * 384 + c];
        x[xbase + c] = y;
    }
}

__global__ __launch_bounds__(256) void cls_kernel(
    const float* __restrict__ ct, const float* __restrict__ cp, float* __restrict__ x)
{
    int idx = blockIdx.x * 256 + threadIdx.x;
    if (idx >= 8 * 384) return;
    int c = idx % 384; int b = idx / 384;
    x[(size_t)b * 513 * 384 + c] = ct[c] + cp[c];
}

// ---------------- V transpose: qkv f16 -> vT[bh][64 d][576 j] (zero-padded) ----------------
__global__ __launch_bounds__(256) void vtrans_kernel(
    const f16* __restrict__ qkv, f16* __restrict__ vT)
{
    __shared__ f16 tile[64][72];
    int jt = blockIdx.x; int bh = blockIdx.y; int h = bh % 6; int b = bh / 6;
    int tid = threadIdx.x;
    int jr = tid >> 2, dseg = (tid & 3) * 16;
    int j = jt * 64 + jr;
    uint4 v0 = make_uint4(0u, 0u, 0u, 0u), v1 = v0;
    if (j < 513) {
        const f16* p = qkv + ((size_t)(b * 513 + j)) * 1152 + 768 + h * 64 + dseg;
        v0 = *(const uint4*)(p); v1 = *(const uint4*)(p + 8);
    }
    *(uint4*)(&tile[jr][dseg]) = v0;
    *(uint4*)(&tile[jr][dseg + 8]) = v1;
    __syncthreads();
    int d = tid >> 2, jseg = (tid & 3) * 16;
    f16 buf[16];
    #pragma unroll
    for (int e = 0; e < 16; e++) buf[e] = tile[jseg + e][d];
    f16* op = vT + ((size_t)bh * 64 + d) * 576 + jt * 64 + jseg;
    *(uint4*)(op) = *(uint4*)(buf);
    *(uint4*)(op + 8) = *(uint4*)(buf + 8);
}

// ---------------- MFMA flash attention: 4 independent waves/block, 16 q-rows/wave ----------------
__global__ __launch_bounds__(256) void fattn_h_kernel(
    const f16* __restrict__ qkv, const f16* __restrict__ vT, f16* __restrict__ out)
{
    __shared__ __align__(16) f16 Pl[4][16][72];
    int qt = blockIdx.x;
    int bh = blockIdx.y; int h = bh % 6; int b = bh / 6;
    int tid = threadIdx.x;
    int w = tid >> 6, lane = tid & 63;
    int l15 = lane & 15, g = lane >> 4;
    int q0w = qt * 64 + w * 16;
    if (q0w > 512) return;                 // no barriers in this kernel
    const size_t RS = 1152;
    const f16* qbase = qkv + (size_t)b * 513 * RS + h * 64;
    const f16* kbase = qbase + 384;
    const f16* vtb = vT + (size_t)bh * 64 * 576;

    // Q fragments (2 K-steps of 32)
    f16x8 qf[2];
    {
        int qrow = q0w + l15; if (qrow > 512) qrow = 512;
        const f16* qp = qbase + (size_t)qrow * RS + g * 8;
        qf[0] = *(const f16x8*)(qp);
        qf[1] = *(const f16x8*)(qp + 32);
    }

    f32x4v zero = {0.f, 0.f, 0.f, 0.f};
    f32x4v O[4]; float m[4], l[4];
    #pragma unroll
    for (int i = 0; i < 4; i++) { O[i] = zero; m[i] = -INFINITY; l[i] = 0.f; }

    int jt0 = 0;
    if (q0w > 0) { int fmin = (q0w - 1) >> 4; jt0 = (fmin * 16 + 1) >> 6; }

    for (int jt = jt0; jt < 9; jt++) {
        int j0 = jt * 64;
        // ---- QK^T: S[16q][64j] per wave ----
        f32x4v S[4];
        #pragma unroll
        for (int jf = 0; jf < 4; jf++) S[jf] = zero;
        #pragma unroll
        for (int s = 0; s < 2; s++) {
            #pragma unroll
            for (int jf = 0; jf < 4; jf++) {
                int j = j0 + jf * 16 + l15; if (j > 512) j = 512;
                f16x8 kf = *(const f16x8*)(kbase + (size_t)j * RS + s * 32 + g * 8);
                S[jf] = __builtin_amdgcn_mfma_f32_16x16x32_f16(qf[s], kf, S[jf], 0, 0, 0);
            }
        }
        // ---- mask + online softmax (register, shfl over 16-group) ----
        float pj[4][4];   // [jf][reg]
        #pragma unroll
        for (int r = 0; r < 4; r++) {
            int qi = q0w + 4 * g + r;
            int fi = (qi == 0) ? -1 : ((qi - 1) >> 4);
            float mx = -INFINITY;
            #pragma unroll
            for (int jf = 0; jf < 4; jf++) {
                int j = j0 + jf * 16 + l15;
                bool valid = (qi < 513) && (j < 513) &&
                             !((qi != 0) && ((j == 0) || (((j - 1) >> 4) < fi)));
                float sv = valid ? S[jf][r] * 0.125f : -INFINITY;
                pj[jf][r] = sv;
                mx = fmaxf(mx, sv);
            }
            mx = fmaxf(mx, __shfl_xor(mx, 1));
            mx = fmaxf(mx, __shfl_xor(mx, 2));
            mx = fmaxf(mx, __shfl_xor(mx, 4));
            mx = fmaxf(mx, __shfl_xor(mx, 8));
            float mn = fmaxf(m[r], mx);
            float alpha = (m[r] == -INFINITY) ? 0.f : __expf(m[r] - mn);
            float ls = 0.f;
            #pragma unroll
            for (int jf = 0; jf < 4; jf++) {
                float p = (pj[jf][r] == -INFINITY) ? 0.f : __expf(pj[jf][r] - mn);
                pj[jf][r] = p; ls += p;
            }
            ls += __shfl_xor(ls, 1); ls += __shfl_xor(ls, 2);
            ls += __shfl_xor(ls, 4); ls += __shfl_xor(ls, 8);
            l[r] = alpha * l[r] + ls;
            m[r] = mn;
            #pragma unroll
            for (int df = 0; df < 4; df++) O[df][r] *= alpha;
        }
        // ---- P -> LDS (per-wave private region; same-wave visibility) ----
        #pragma unroll
        for (int jf = 0; jf < 4; jf++)
            #pragma unroll
            for (int r = 0; r < 4; r++)
                Pl[w][4 * g + r][jf * 16 + l15] = (f16)pj[jf][r];
        // ---- PV: O[16q][64d] += P[16q][64j] * V[64j][64d] ----
        #pragma unroll
        for (int s = 0; s < 2; s++) {
            f16x8 pf = *(const f16x8*)(&Pl[w][l15][s * 32 + g * 8]);
            #pragma unroll
            for (int df = 0; df < 4; df++) {
                f16x8 vf = *(const f16x8*)(vtb + (size_t)(df * 16 + l15) * 576 + j0 + s * 32 + g * 8);
                O[df] = __builtin_amdgcn_mfma_f32_16x16x32_f16(pf, vf, O[df], 0, 0, 0);
            }
        }
    }

    // ---- write out ----
    #pragma unroll
    for (int r = 0; r < 4; r++) {
        int qi = q0w + 4 * g + r;
        if (qi > 512) continue;
        float rl = 1.0f / l[r];
        #pragma unroll
        for (int df = 0; df < 4; df++)
            out[(size_t)(b * 513 + qi) * 384 + h * 64 + df * 16 + l15] = (f16)(O[df][r] * rl);
    }
}

// ---------------- head: LN + MLP(384->384 gelu ->2) + sigmoid, 384 threads ----------------
__global__ __launch_bounds__(384) void head_kernel(
    const float* __restrict__ x, const float* __restrict__ lg, const float* __restrict__ lb,
    const float* __restrict__ w1, const float* __restrict__ b1,
    const float* __restrict__ w2, const float* __restrict__ b2,
    float* __restrict__ out)
{
    int b = blockIdx.x; int t = threadIdx.x;
    __shared__ float hs[384], h1[384];
    __shared__ float rs[6], rs2[6];
    const float* xp = x + (size_t)b * 513 * 384;
    float v = xp[t];
    float s = v, s2 = v * v;
    #pragma unroll
    for (int off = 32; off >= 1; off >>= 1) {
        s += __shfl_down(s, off); s2 += __shfl_down(s2, off);
    }
    if ((t & 63) == 0) { rs[t >> 6] = s; rs2[t >> 6] = s2; }
    __syncthreads();
    float S = 0.f, S2 = 0.f;
    #pragma unroll
    for (int i = 0; i < 6; i++) { S += rs[i]; S2 += rs2[i]; }
    float mu = S * (1.f / 384.f);
    float var = S2 * (1.f / 384.f) - mu * mu;
    float rstd = rsqrtf(var + EPSV);
    hs[t] = (v - mu) * rstd * lg[t] + lb[t];
    __syncthreads();
    const float* wr = w1 + (size_t)t * 384;
    float acc = b1[t];
    for (int c = 0; c < 384; c += 4) {
        float4 w4 = *reinterpret_cast<const float4*>(wr + c);
        acc += w4.x * hs[c] + w4.y * hs[c + 1] + w4.z * hs[c + 2] + w4.w * hs[c + 3];
    }
    h1[t] = gelu_f(acc);
    __syncthreads();
    float p0 = h1[t] * w2[t], p1 = h1[t] * w2[384 + t];
    #pragma unroll
    for (int off = 32; off >= 1; off >>= 1) {
        p0 += __shfl_down(p0, off); p1 += __shfl_down(p1, off);
    }
    if ((t & 63) == 0) { rs[t >> 6] = p0; rs2[t >> 6] = p1; }
    __syncthreads();
    if (t == 0) {
        float a0 = b2[0], a1 = b2[1];
        #pragma unroll
        for (int i = 0; i < 6; i++) { a0 += rs[i]; a1 += rs2[i]; }
        out[b * 2 + 0] = 1.f / (1.f + expf(-a0));
        out[b * 2 + 1] = 1.f / (1.f + expf(-a1));
    }
}

static inline int cdiv(int a, int b) { return (a + b - 1) / b; }

extern "C" void kernel_launch(void* const* d_in, const int* in_sizes, int n_in,
                              void* d_out, int out_size, void* d_ws, size_t ws_size,
                              hipStream_t stream)
{
    const float* frames  = (const float*)d_in[0];
    const float* conv1_w = (const float*)d_in[1];
    const float* bn1_g = (const float*)d_in[2]; const float* bn1_b = (const float*)d_in[3];
    const float* bn1_m = (const float*)d_in[4]; const float* bn1_v = (const float*)d_in[5];
    const float* conv2_w = (const float*)d_in[6];
    const float* bn2_g = (const float*)d_in[7]; const float* bn2_b = (const float*)d_in[8];
    const float* bn2_m = (const float*)d_in[9]; const float* bn2_v = (const float*)d_in[10];
    const float* conv3_w = (const float*)d_in[11];
    const float* bn3_g = (const float*)d_in[12]; const float* bn3_b = (const float*)d_in[13];
    const float* bn3_m = (const float*)d_in[14]; const float* bn3_v = (const float*)d_in[15];
    const float* proj_w = (const float*)d_in[16];
    const float* dw_w = (const float*)d_in[17]; const float* dw_b = (const float*)d_in[18];
    const float* pw_w = (const float*)d_in[19]; const float* pw_b = (const float*)d_in[20];
    const float* tnorm_g = (const float*)d_in[21]; const float* tnorm_b = (const float*)d_in[22];
    const float* frame_pos = (const float*)d_in[23];
    const float* patch_pos = (const float*)d_in[24];
    const float* cls_token = (const float*)d_in[25];
    const float* cls_pos = (const float*)d_in[26];
    const float* qkv_w = (const float*)d_in[27]; const float* qkv_b = (const float*)d_in[28];
    const float* out_w = (const float*)d_in[29]; const float* out_b = (const float*)d_in[30];
    const float* ln1_g = (const float*)d_in[31]; const float* ln1_b = (const float*)d_in[32];
    const float* ln2_g = (const float*)d_in[33]; const float* ln2_b = (const float*)d_in[34];
    const float* ffn_w1 = (const float*)d_in[35]; const float* ffn_b1 = (const float*)d_in[36];
    const float* ffn_w2 = (const float*)d_in[37]; const float* ffn_b2 = (const float*)d_in[38];
    const float* head_ln_g = (const float*)d_in[39]; const float* head_ln_b = (const float*)d_in[40];
    const float* head_w1 = (const float*)d_in[41]; const float* head_b1 = (const float*)d_in[42];
    const float* head_w2 = (const float*)d_in[43]; const float* head_b2 = (const float*)d_in[44];
    (void)in_sizes; (void)n_in; (void)out_size; (void)ws_size;

    char* base = (char*)d_ws;
    size_t off = 0;
    auto alloc = [&](size_t bytes) { void* p = base + off; off = (off + bytes + 255) & ~(size_t)255; return p; };

    // f16 weights
    f16* projw16 = (f16*)alloc(384 * 128 * 2);
    f16* pw16    = (f16*)alloc((size_t)2 * 384 * 384 * 2);
    f16* qkvw16  = (f16*)alloc((size_t)6 * 1152 * 384 * 2);
    f16* outw16  = (f16*)alloc((size_t)6 * 384 * 384 * 2);
    f16* f1w16   = (f16*)alloc((size_t)6 * 1536 * 384 * 2);
    f16* f2w16   = (f16*)alloc((size_t)6 * 384 * 1536 * 2);
    f16* c2w16   = (f16*)alloc((size_t)64 * 288 * 2);
    f16* c3w16   = (f16*)alloc((size_t)128 * 576 * 2);
    // activations
    float* tokens = (float*)alloc((size_t)4096 * 384 * 4);
    f16* pooled   = (f16*)alloc((size_t)4096 * 128 * 2);
    f16* c1h = (f16*)alloc((size_t)64 * 64 * 64 * 32 * 2);
    f16* c2h = (f16*)alloc((size_t)64 * 32 * 32 * 64 * 2);
    f16* c3h = (f16*)alloc((size_t)64 * 16 * 16 * 128 * 2);
    float* tc = (float*)alloc((size_t)4096 * 384 * 4);
    float* mA = (float*)alloc((size_t)4096 * 384 * 4);
    float* mB = (float*)alloc((size_t)4096 * 384 * 4);
    f16*   mh = (f16*)alloc((size_t)4096 * 384 * 2);
    float* xb   = (float*)alloc((size_t)8 * 513 * 384 * 4);
    f16*   hb   = (f16*)alloc((size_t)8 * 513 * 384 * 2);
    f16*   qkvb = (f16*)alloc((size_t)8 * 513 * 1152 * 2);
    f16*   vTb  = (f16*)alloc((size_t)48 * 64 * 576 * 2);
    f16*   ob   = (f16*)alloc((size_t)8 * 513 * 384 * 2);
    f16*   ffb  = (f16*)alloc((size_t)8 * 513 * 1536 * 2);

    // ---------- weight conversion ----------
    auto cvt = [&](const float* src, f16* dst, int n) {
        cvt_h_kernel<<<min(cdiv(n, 256), 2048), 256, 0, stream>>>(src, dst, n);
    };
    cvt(proj_w, projw16, 384 * 128);
    cvt(pw_w, pw16, 2 * 384 * 384);
    cvt(qkv_w, qkvw16, 6 * 1152 * 384);
    cvt(out_w, outw16, 6 * 384 * 384);
    cvt(ffn_w1, f1w16, 6 * 1536 * 384);
    cvt(ffn_w2, f2w16, 6 * 384 * 1536);
    conv_w_reorder_kernel<<<cdiv(64 * 288, 256), 256, 0, stream>>>(conv2_w, c2w16, 64, 32);
    conv_w_reorder_kernel<<<cdiv(128 * 576, 256), 256, 0, stream>>>(conv3_w, c3w16, 128, 64);

    // ---------- conv stem, 4 chunks of 64 frames ----------
    for (int ch = 0; ch < 4; ch++) {
        const float* fch = frames + (size_t)ch * 64 * 16384;
        conv1_tile_kernel<<<64 * 16, 256, 0, stream>>>(
            fch, conv1_w, bn1_g, bn1_b, bn1_m, bn1_v, c1h);
        convg_kernel<32, 64, 64><<<dim3(1024, 1), 256, 0, stream>>>(
            c1h, c2w16, bn2_g, bn2_b, bn2_m, bn2_v, c2h);
        convg_kernel<64, 32, 128><<<dim3(256, 2), 256, 0, stream>>>(
            c2h, c3w16, bn3_g, bn3_b, bn3_m, bn3_v, c3h);
        poolh_kernel<<<64, 256, 0, stream>>>(c3h, pooled + (size_t)ch * 1024 * 128, 64);
    }
    gemm_h_kernel<0, 0><<<dim3(6, 64), 256, 0, stream>>>(
        pooled, projw16, nullptr, nullptr, tokens, 4096, 384, 128);

    // ---------- temporal mixer ----------
    tok2tc_kernel<<<cdiv(8 * 32 * 16 * 384, 256), 256, 0, stream>>>(tokens, tc);
    hipMemcpyAsync(mA, tc, (size_t)4096 * 384 * sizeof(float), hipMemcpyDeviceToDevice, stream);
    float* cur = mA; float* alt = mB;
    for (int it = 0; it < 2; it++) {
        int dil = (it == 0) ? 1 : 2;
        dwconv_kernel<<<cdiv(128 * 32 * 384, 256), 256, 0, stream>>>(
            cur, dw_w + (size_t)it * 384 * 3, dw_b + (size_t)it * 384, mh, dil);
        gemm_h_kernel<0, 0><<<dim3(6, 64), 256, 0, stream>>>(
            mh, pw16 + (size_t)it * 384 * 384, pw_b + (size_t)it * 384, cur,
            alt, 4096, 384, 384);
        float* tmp = cur; cur = alt; alt = tmp;
    }

    // ---------- build transformer input x ----------
    build_x_kernel<<<128 * 32, 128, 0, stream>>>(
        cur, tc, tnorm_g, tnorm_b, frame_pos, patch_pos, xb);
    cls_kernel<<<cdiv(8 * 384, 256), 256, 0, stream>>>(cls_token, cls_pos, xb);

    // ---------- transformer ----------
    const int M = 8 * 513;   // 4104
    const int MG = cdiv(M, 64);   // 65
    for (int l = 0; l < 6; l++) {
        ln_kernel<<<M, 128, 0, stream>>>(xb,
            ln1_g + (size_t)l * 384, ln1_b + (size_t)l * 384, hb, M);
        gemm_h_kernel<1, 0><<<dim3(18, MG), 256, 0, stream>>>(
            hb, qkvw16 + (size_t)l * 1152 * 384, qkv_b + (size_t)l * 1152,
            nullptr, qkvb, M, 1152, 384);
        vtrans_kernel<<<dim3(9, 48), 256, 0, stream>>>(qkvb, vTb);
        fattn_h_kernel<<<dim3(9, 48), 256, 0, stream>>>(qkvb, vTb, ob);
        gemm_h_kernel<0, 0><<<dim3(6, MG), 256, 0, stream>>>(
            ob, outw16 + (size_t)l * 384 * 384, out_b + (size_t)l * 384,
            xb, xb, M, 384, 384);
        ln_kernel<<<M, 128, 0, stream>>>(xb,
            ln2_g + (size_t)l * 384, ln2_b + (size_t)l * 384, hb, M);
        gemm_h_kernel<1, 1><<<dim3(24, MG), 256, 0, stream>>>(
            hb, f1w16 + (size_t)l * 1536 * 384, ffn_b1 + (size_t)l * 1536,
            nullptr, ffb, M, 1536, 384);
        gemm_h_kernel<0, 0><<<dim3(6, MG), 256, 0, stream>>>(
            ffb, f2w16 + (size_t)l * 384 * 1536, ffn_b2 + (size_t)l * 384,
            xb, xb, M, 384, 1536);
    }

    // ---------- head ----------
    head_kernel<<<8, 384, 0, stream>>>(
        xb, head_ln_g, head_ln_b, head_w1, head_b1, head_w2, head_b2, (float*)d_out);
}

// Round 5
// 1127.555 us; speedup vs baseline: 10.6415x; 1.1309x over previous
//
#include <hip/hip_runtime.h>
#include <hip/hip_fp16.h>
#include <cstddef>

#define EPSV 1e-5f

typedef _Float16 f16;
typedef _Float16 f16x8 __attribute__((ext_vector_type(8)));
typedef float f32x4v __attribute__((ext_vector_type(4)));

__device__ __forceinline__ float gelu_f(float x) {
    return 0.5f * x * (1.0f + erff(x * 0.7071067811865476f));
}

// fast GELU (tanh form); max abs err ~1e-3, fine under 1e-2 output threshold
__device__ __forceinline__ float gelu_fast(float x) {
    float y = 0.7978845608f * (x + 0.044715f * x * x * x);
    y = fminf(fmaxf(y, -10.f), 10.f);
    float e = __expf(2.f * y);
    float t = (e - 1.f) / (e + 1.f);
    return 0.5f * x * (1.f + t);
}

// ---------------- all-weights f32 -> f16 convert (one dispatch) ----------------
__global__ __launch_bounds__(256) void cvt_all_kernel(
    const float* __restrict__ p0, const float* __restrict__ p1,
    const float* __restrict__ p2, const float* __restrict__ p3,
    const float* __restrict__ p4, const float* __restrict__ p5,
    f16* __restrict__ dst)
{
    const int n = 10960896;
    for (int i = blockIdx.x * 256 + threadIdx.x; i < n; i += gridDim.x * 256) {
        const float* s; int off;
        if      (i <   49152) { s = p0; off = i; }
        else if (i <  344064) { s = p1; off = i -   49152; }
        else if (i < 2998272) { s = p2; off = i -  344064; }
        else if (i < 3883008) { s = p3; off = i - 2998272; }
        else if (i < 7421952) { s = p4; off = i - 3883008; }
        else                  { s = p5; off = i - 7421952; }
        dst[i] = (f16)s[off];
    }
}

// ---------------- conv weight reorder: [co][ci][3][3] -> [co][tap*CI+ci] f16 ----------------
__global__ __launch_bounds__(256) void conv_w_reorder_kernel(
    const float* __restrict__ w, f16* __restrict__ out, int CO, int CI)
{
    int n = CO * CI * 9;
    for (int i = blockIdx.x * 256 + threadIdx.x; i < n; i += gridDim.x * 256) {
        int t = i % 9; int r = i / 9;
        int ci = r % CI; int co = r / CI;
        out[(size_t)co * CI * 9 + t * CI + ci] = (f16)w[i];
    }
}

// ---------------- conv1: 5x5 s2 p2, wave-per-8co, scalar weights, NHWC f16 out ----------------
__global__ __launch_bounds__(256) void conv1_wave_kernel(
    const float* __restrict__ in, const float* __restrict__ w,
    const float* __restrict__ g, const float* __restrict__ bt,
    const float* __restrict__ mn, const float* __restrict__ vr,
    f16* __restrict__ out)
{
    __shared__ float inp[35][37];
    int bid = blockIdx.x;
    int n = bid >> 4; int tile = bid & 15;
    int ty0 = (tile >> 2) * 16, tx0 = (tile & 3) * 16;
    int t = threadIdx.x;
    const float* ip = in + (size_t)n * 16384;
    for (int e = t; e < 35 * 36; e += 256) {
        int r = e / 36, c = e - r * 36;
        int iy = ty0 * 2 - 2 + r, ix = tx0 * 2 - 2 + c;
        inp[r][c] = ((unsigned)iy < 128u && (unsigned)ix < 128u) ? ip[iy * 128 + ix] : 0.f;
    }
    __syncthreads();
    int wv = __builtin_amdgcn_readfirstlane(t >> 6);   // wave id, provably uniform
    int lane = t & 63;
    int cobase = wv * 8;
    float sc[8], be[8];
    #pragma unroll
    for (int c = 0; c < 8; c++) {
        int co = cobase + c;
        float iv = g[co] * rsqrtf(vr[co] + EPSV);
        sc[c] = iv; be[c] = bt[co] - mn[co] * iv;
    }
    #pragma unroll
    for (int pix = 0; pix < 4; pix++) {
        int p = pix * 64 + lane;
        int py = p >> 4, px = p & 15;
        float r0[25];
        #pragma unroll
        for (int ky = 0; ky < 5; ky++)
            #pragma unroll
            for (int kx = 0; kx < 5; kx++)
                r0[ky * 5 + kx] = inp[2 * py + ky][2 * px + kx];
        f16 o[8];
        #pragma unroll
        for (int c = 0; c < 8; c++) {
            const float* wp = w + (cobase + c) * 25;   // wave-uniform -> s_load
            float acc = 0.f;
            #pragma unroll
            for (int k = 0; k < 25; k++) acc += wp[k] * r0[k];
            o[c] = (f16)gelu_fast(acc * sc[c] + be[c]);
        }
        size_t ob = (((size_t)n * 64 + ty0 + py) * 64 + tx0 + px) * 32 + cobase;
        *(uint4*)(out + ob) = *(uint4*)o;
    }
}

// ---------------- implicit-GEMM conv 3x3 s2 p1, NHWC f16, MFMA ----------------
template<int CI, int HI, int CO>
__global__ __launch_bounds__(256) void convg_kernel(
    const f16* __restrict__ in, const f16* __restrict__ wr_,
    const float* __restrict__ g, const float* __restrict__ bt,
    const float* __restrict__ mn, const float* __restrict__ vr,
    f16* __restrict__ out)
{
    constexpr int HO = HI / 2;
    constexpr int HOB = (HO == 32) ? 5 : 4;
    constexpr int K = 9 * CI;
    __shared__ __align__(16) f16 As[64 * 40];
    __shared__ __align__(16) f16 Bs[64 * 40];
    int tid = threadIdx.x;
    int bm = blockIdx.x * 64;
    int bn = blockIdx.y * 64;
    int lrow = tid >> 2, lseg = tid & 3;
    int w = tid >> 6, lane = tid & 63;
    int wr = (w >> 1) * 32, wc = (w & 1) * 32;
    int l15 = lane & 15, l4 = lane >> 4;
    int gp = bm + lrow;
    int pn = gp >> (2 * HOB);
    int prem = gp & ((1 << (2 * HOB)) - 1);
    int oy = prem >> HOB, ox = prem & (HO - 1);

    f32x4v zero = {0.f, 0.f, 0.f, 0.f};
    f32x4v acc[2][2];
    acc[0][0] = zero; acc[0][1] = zero; acc[1][0] = zero; acc[1][1] = zero;

    for (int k0 = 0; k0 < K; k0 += 32) {
        int tap = k0 / CI;
        int cio = k0 - tap * CI;
        int ky = tap / 3, kx = tap - ky * 3;
        int iy = oy * 2 - 1 + ky, ix = ox * 2 - 1 + kx;
        uint4 av = make_uint4(0u, 0u, 0u, 0u);
        if ((unsigned)iy < (unsigned)HI && (unsigned)ix < (unsigned)HI)
            av = *(const uint4*)(in + (((size_t)(pn * HI + iy)) * HI + ix) * CI + cio + lseg * 8);
        *(uint4*)(&As[lrow * 40 + lseg * 8]) = av;
        uint4 bv = *(const uint4*)(wr_ + (size_t)(bn + lrow) * K + k0 + lseg * 8);
        *(uint4*)(&Bs[lrow * 40 + lseg * 8]) = bv;
        __syncthreads();
        f16x8 a0 = *(const f16x8*)(&As[(wr + l15) * 40 + l4 * 8]);
        f16x8 a1 = *(const f16x8*)(&As[(wr + 16 + l15) * 40 + l4 * 8]);
        f16x8 b0 = *(const f16x8*)(&Bs[(wc + l15) * 40 + l4 * 8]);
        f16x8 b1 = *(const f16x8*)(&Bs[(wc + 16 + l15) * 40 + l4 * 8]);
        acc[0][0] = __builtin_amdgcn_mfma_f32_16x16x32_f16(a0, b0, acc[0][0], 0, 0, 0);
        acc[0][1] = __builtin_amdgcn_mfma_f32_16x16x32_f16(a0, b1, acc[0][1], 0, 0, 0);
        acc[1][0] = __builtin_amdgcn_mfma_f32_16x16x32_f16(a1, b0, acc[1][0], 0, 0, 0);
        acc[1][1] = __builtin_amdgcn_mfma_f32_16x16x32_f16(a1, b1, acc[1][1], 0, 0, 0);
        __syncthreads();
    }
    float inv[2], beta[2];
    #pragma unroll
    for (int ni = 0; ni < 2; ni++) {
        int col = bn + wc + ni * 16 + l15;
        float iv = g[col] * rsqrtf(vr[col] + EPSV);
        inv[ni] = iv; beta[ni] = bt[col] - mn[col] * iv;
    }
    #pragma unroll
    for (int mi = 0; mi < 2; mi++) {
        #pragma unroll
        for (int q = 0; q < 4; q++) {
            int pixel = bm + wr + mi * 16 + l4 * 4 + q;
            #pragma unroll
            for (int ni = 0; ni < 2; ni++) {
                int col = bn + wc + ni * 16 + l15;
                float v = acc[mi][ni][q] * inv[ni] + beta[ni];
                out[(size_t)pixel * CO + col] = (f16)gelu_fast(v);
            }
        }
    }
}

// ---------------- 4x4 avg pool NHWC f16 ----------------
__global__ __launch_bounds__(256) void poolh_kernel(
    const f16* __restrict__ in, f16* __restrict__ out, int NC)
{
    int idx = blockIdx.x * 256 + threadIdx.x;
    if (idx >= NC * 16 * 16) return;
    int cc = idx & 15; int npl = idx >> 4;
    int c0 = cc * 8;
    int n = npl >> 4; int p = npl & 15;
    int ph = p >> 2, pw = p & 3;
    const f16* base = in + (((size_t)(n * 16 + ph * 4)) * 16 + pw * 4) * 128 + c0;
    float s[8] = {};
    #pragma unroll
    for (int dy = 0; dy < 4; dy++)
        #pragma unroll
        for (int dx = 0; dx < 4; dx++) {
            f16x8 v = *(const f16x8*)(base + (dy * 16 + dx) * 128);
            #pragma unroll
            for (int u = 0; u < 8; u++) s[u] += (float)v[u];
        }
    f16* op = out + (size_t)npl * 128 + c0;
    #pragma unroll
    for (int u = 0; u < 8; u++) op[u] = (f16)(s[u] * 0.0625f);
}

// ---------------- MFMA f16 NT GEMM; VTRANS: V-col blocks write transposed vT ----------------
template<int OUTF16, int ACT, int VTRANS>
__global__ __launch_bounds__(256) void gemm_h_kernel(
    const f16* __restrict__ A, const f16* __restrict__ B,
    const float* __restrict__ bias, const float* __restrict__ res,
    void* __restrict__ Cv, f16* __restrict__ vT, int M, int N, int K)
{
    __shared__ __align__(16) f16 ABs[2 * 64 * 40];
    f16* As = ABs;
    f16* Bs = ABs + 64 * 40;
    int tid = threadIdx.x;
    int bm = blockIdx.y * 64, bn = blockIdx.x * 64;
    int lrow = tid >> 2, lseg = tid & 3;
    int w = tid >> 6, lane = tid & 63;
    int wr = (w >> 1) * 32, wc = (w & 1) * 32;
    int l15 = lane & 15, l4 = lane >> 4;
    f32x4v zero = {0.f, 0.f, 0.f, 0.f};
    f32x4v acc[2][2];
    acc[0][0] = zero; acc[0][1] = zero; acc[1][0] = zero; acc[1][1] = zero;
    int arow = bm + lrow;
    const f16* ap = A + (size_t)arow * K + lseg * 8;
    const f16* bp = B + (size_t)(bn + lrow) * K + lseg * 8;
    bool aok = (arow < M);
    for (int k0 = 0; k0 < K; k0 += 32) {
        uint4 av = make_uint4(0u, 0u, 0u, 0u);
        if (aok) av = *(const uint4*)(ap + k0);
        *(uint4*)(&As[lrow * 40 + lseg * 8]) = av;
        uint4 bv = *(const uint4*)(bp + k0);
        *(uint4*)(&Bs[lrow * 40 + lseg * 8]) = bv;
        __syncthreads();
        f16x8 a0 = *(const f16x8*)(&As[(wr + l15) * 40 + l4 * 8]);
        f16x8 a1 = *(const f16x8*)(&As[(wr + 16 + l15) * 40 + l4 * 8]);
        f16x8 b0 = *(const f16x8*)(&Bs[(wc + l15) * 40 + l4 * 8]);
        f16x8 b1 = *(const f16x8*)(&Bs[(wc + 16 + l15) * 40 + l4 * 8]);
        acc[0][0] = __builtin_amdgcn_mfma_f32_16x16x32_f16(a0, b0, acc[0][0], 0, 0, 0);
        acc[0][1] = __builtin_amdgcn_mfma_f32_16x16x32_f16(a0, b1, acc[0][1], 0, 0, 0);
        acc[1][0] = __builtin_amdgcn_mfma_f32_16x16x32_f16(a1, b0, acc[1][0], 0, 0, 0);
        acc[1][1] = __builtin_amdgcn_mfma_f32_16x16x32_f16(a1, b1, acc[1][1], 0, 0, 0);
        __syncthreads();
    }
    if (VTRANS && bn >= 768) {
        // V columns: bias-add, transpose 64x64 C-tile in LDS, write vT[bh][d][j]
        f16* tile = ABs;   // [64][66]
        #pragma unroll
        for (int mi = 0; mi < 2; mi++)
            #pragma unroll
            for (int q = 0; q < 4; q++) {
                int rl = wr + mi * 16 + l4 * 4 + q;
                #pragma unroll
                for (int ni = 0; ni < 2; ni++) {
                    int dl = wc + ni * 16 + l15;
                    float v = acc[mi][ni][q] + bias[bn + dl];
                    tile[dl * 66 + rl] = (f16)v;
                }
            }
        __syncthreads();
        int h = (bn - 768) >> 6;
        int j = tid & 63, dbase = tid >> 6;
        int trow = bm + j;
        if (trow < M) {
            int b = trow / 513;
            int jj = trow - b * 513;
            f16* vb = vT + ((size_t)(b * 6 + h) * 64) * 576 + jj;
            #pragma unroll
            for (int it = 0; it < 16; it++) {
                int d = dbase * 16 + it;
                vb[(size_t)d * 576] = tile[d * 66 + j];
            }
        }
        return;
    }
    #pragma unroll
    for (int mi = 0; mi < 2; mi++) {
        #pragma unroll
        for (int q = 0; q < 4; q++) {
            int row = bm + wr + mi * 16 + l4 * 4 + q;
            if (row >= M) continue;
            #pragma unroll
            for (int ni = 0; ni < 2; ni++) {
                int col = bn + wc + ni * 16 + l15;
                float v = acc[mi][ni][q];
                if (bias) v += bias[col];
                if (ACT == 1) v = gelu_fast(v);
                if (res) v += res[(size_t)row * N + col];
                if (OUTF16) ((f16*)Cv)[(size_t)row * N + col] = (f16)v;
                else ((float*)Cv)[(size_t)row * N + col] = v;
            }
        }
    }
}

// ---------------- tokens (b,t,p,d) f32 -> tc (b*16+p, t, d) f32 ----------------
__global__ __launch_bounds__(256) void tok2tc_kernel(
    const float* __restrict__ in, float* __restrict__ out)
{
    int idx = blockIdx.x * 256 + threadIdx.x;
    if (idx >= 8 * 32 * 16 * 384) return;
    int d = idx % 384; int t2 = idx / 384;
    int p = t2 & 15; t2 >>= 4;
    int t = t2 & 31; int b = t2 >> 5;
    out[(((size_t)(b * 16 + p) * 32 + t) * 384) + d] = in[idx];
}

// ---------------- depthwise temporal conv + bias + gelu -> f16 ----------------
__global__ __launch_bounds__(256) void dwconv_kernel(
    const float* __restrict__ in, const float* __restrict__ w,
    const float* __restrict__ bias, f16* __restrict__ out, int dil)
{
    int idx = blockIdx.x * 256 + threadIdx.x;
    if (idx >= 128 * 32 * 384) return;
    int d = idx % 384; int t = (idx / 384) & 31; int s = idx / (384 * 32);
    const float* ip = in + (size_t)s * 32 * 384 + d;
    float acc = bias[d];
    #pragma unroll
    for (int k = 0; k < 3; k++) {
        int tt = t + (k - 1) * dil;
        if ((unsigned)tt < 32u) acc += w[d * 3 + k] * ip[tt * 384];
    }
    out[idx] = (f16)gelu_fast(acc);
}

// ---------------- LayerNorm over 384, f32 in -> f16 out ----------------
__global__ __launch_bounds__(128) void ln_kernel(
    const float* __restrict__ in,
    const float* __restrict__ g, const float* __restrict__ b,
    f16* __restrict__ out, int rows)
{
    int row = blockIdx.x;
    if (row >= rows) return;
    int t = threadIdx.x;
    const float* ip = in + (size_t)row * 384;
    __shared__ float red[128], red2[128];
    float x[3]; float s = 0.f, s2 = 0.f;
    #pragma unroll
    for (int j = 0; j < 3; j++) {
        float v = ip[t + 128 * j];
        x[j] = v; s += v; s2 += v * v;
    }
    red[t] = s; red2[t] = s2; __syncthreads();
    for (int off = 64; off >= 1; off >>= 1) {
        if (t < off) { red[t] += red[t + off]; red2[t] += red2[t + off]; }
        __syncthreads();
    }
    float mu = red[0] * (1.f / 384.f);
    float var = red2[0] * (1.f / 384.f) - mu * mu;
    float rs = rsqrtf(var + EPSV);
    #pragma unroll
    for (int j = 0; j < 3; j++) {
        int c = t + 128 * j;
        out[(size_t)row * 384 + c] = (f16)((x[j] - mu) * rs * g[c] + b[c]);
    }
}

// ---------------- mixer-final LN + positional add, scatter into x (f32) ----------------
__global__ __launch_bounds__(128) void build_x_kernel(
    const float* __restrict__ mix, const float* __restrict__ tc,
    const float* __restrict__ tg, const float* __restrict__ tb,
    const float* __restrict__ fpos, const float* __restrict__ ppos,
    float* __restrict__ x)
{
    int row = blockIdx.x;
    int t = row & 31; int bp = row >> 5;
    int p = bp & 15; int b = bp >> 4;
    int tid = threadIdx.x;
    const float* ip = mix + (size_t)row * 384;
    const float* ip2 = tc + (size_t)row * 384;
    __shared__ float red[128], red2[128];
    float v[3]; float s = 0.f, s2 = 0.f;
    #pragma unroll
    for (int j = 0; j < 3; j++) {
        float val = ip[tid + 128 * j] + ip2[tid + 128 * j];
        v[j] = val; s += val; s2 += val * val;
    }
    red[tid] = s; red2[tid] = s2; __syncthreads();
    for (int off = 64; off >= 1; off >>= 1) {
        if (tid < off) { red[tid] += red[tid + off]; red2[tid] += red2[tid + off]; }
        __syncthreads();
    }
    float mu = red[0] * (1.f / 384.f);
    float var = red2[0] * (1.f / 384.f) - mu * mu;
    float rs = rsqrtf(var + EPSV);
    size_t xbase = ((size_t)b * 513 + 1 + t * 16 + p) * 384;
    #pragma unroll
    for (int j = 0; j < 3; j++) {
        int c = tid + 128 * j;
        float y = (v[j] - mu) * rs * tg[c] + tb[c] + fpos[t * 384 + c] + ppos[p * 384 + c];
        x[xbase + c] = y;
    }
}

__global__ __launch_bounds__(256) void cls_kernel(
    const float* __restrict__ ct, const float* __restrict__ cp, float* __restrict__ x)
{
    int idx = blockIdx.x * 256 + threadIdx.x;
    if (idx >= 8 * 384) return;
    int c = idx % 384; int b = idx / 384;
    x[(size_t)b * 513 * 384 + c] = ct[c] + cp[c];
}

// ---------------- MFMA flash attention: 4 independent waves/block, 16 q-rows/wave ----------------
__global__ __launch_bounds__(256) void fattn_h_kernel(
    const f16* __restrict__ qkv, const f16* __restrict__ vT, f16* __restrict__ out)
{
    __shared__ __align__(16) f16 Pl[4][16][72];
    int qt = blockIdx.x;
    int bh = blockIdx.y; int h = bh % 6; int b = bh / 6;
    int tid = threadIdx.x;
    int w = tid >> 6, lane = tid & 63;
    int l15 = lane & 15, g = lane >> 4;
    int q0w = qt * 64 + w * 16;
    if (q0w > 512) return;                 // no barriers in this kernel
    const size_t RS = 1152;
    const f16* qbase = qkv + (size_t)b * 513 * RS + h * 64;
    const f16* kbase = qbase + 384;
    const f16* vtb = vT + (size_t)bh * 64 * 576;

    f16x8 qf[2];
    {
        int qrow = q0w + l15; if (qrow > 512) qrow = 512;
        const f16* qp = qbase + (size_t)qrow * RS + g * 8;
        qf[0] = *(const f16x8*)(qp);
        qf[1] = *(const f16x8*)(qp + 32);
    }

    f32x4v zero = {0.f, 0.f, 0.f, 0.f};
    f32x4v O[4]; float m[4], l[4];
    #pragma unroll
    for (int i = 0; i < 4; i++) { O[i] = zero; m[i] = -INFINITY; l[i] = 0.f; }

    int jt0 = 0;
    if (q0w > 0) { int fmin = (q0w - 1) >> 4; jt0 = (fmin * 16 + 1) >> 6; }

    for (int jt = jt0; jt < 9; jt++) {
        int j0 = jt * 64;
        f32x4v S[4];
        #pragma unroll
        for (int jf = 0; jf < 4; jf++) S[jf] = zero;
        #pragma unroll
        for (int s = 0; s < 2; s++) {
            #pragma unroll
            for (int jf = 0; jf < 4; jf++) {
                int j = j0 + jf * 16 + l15; if (j > 512) j = 512;
                f16x8 kf = *(const f16x8*)(kbase + (size_t)j * RS + s * 32 + g * 8);
                S[jf] = __builtin_amdgcn_mfma_f32_16x16x32_f16(qf[s], kf, S[jf], 0, 0, 0);
            }
        }
        float pj[4][4];
        #pragma unroll
        for (int r = 0; r < 4; r++) {
            int qi = q0w + 4 * g + r;
            int fi = (qi == 0) ? -1 : ((qi - 1) >> 4);
            float mx = -INFINITY;
            #pragma unroll
            for (int jf = 0; jf < 4; jf++) {
                int j = j0 + jf * 16 + l15;
                bool valid = (qi < 513) && (j < 513) &&
                             !((qi != 0) && ((j == 0) || (((j - 1) >> 4) < fi)));
                float sv = valid ? S[jf][r] * 0.125f : -INFINITY;
                pj[jf][r] = sv;
                mx = fmaxf(mx, sv);
            }
            mx = fmaxf(mx, __shfl_xor(mx, 1));
            mx = fmaxf(mx, __shfl_xor(mx, 2));
            mx = fmaxf(mx, __shfl_xor(mx, 4));
            mx = fmaxf(mx, __shfl_xor(mx, 8));
            float mn = fmaxf(m[r], mx);
            float alpha = (m[r] == -INFINITY) ? 0.f : __expf(m[r] - mn);
            float ls = 0.f;
            #pragma unroll
            for (int jf = 0; jf < 4; jf++) {
                float p = (pj[jf][r] == -INFINITY) ? 0.f : __expf(pj[jf][r] - mn);
                pj[jf][r] = p; ls += p;
            }
            ls += __shfl_xor(ls, 1); ls += __shfl_xor(ls, 2);
            ls += __shfl_xor(ls, 4); ls += __shfl_xor(ls, 8);
            l[r] = alpha * l[r] + ls;
            m[r] = mn;
            #pragma unroll
            for (int df = 0; df < 4; df++) O[df][r] *= alpha;
        }
        #pragma unroll
        for (int jf = 0; jf < 4; jf++)
            #pragma unroll
            for (int r = 0; r < 4; r++)
                Pl[w][4 * g + r][jf * 16 + l15] = (f16)pj[jf][r];
        #pragma unroll
        for (int s = 0; s < 2; s++) {
            f16x8 pf = *(const f16x8*)(&Pl[w][l15][s * 32 + g * 8]);
            #pragma unroll
            for (int df = 0; df < 4; df++) {
                f16x8 vf = *(const f16x8*)(vtb + (size_t)(df * 16 + l15) * 576 + j0 + s * 32 + g * 8);
                O[df] = __builtin_amdgcn_mfma_f32_16x16x32_f16(pf, vf, O[df], 0, 0, 0);
            }
        }
    }

    #pragma unroll
    for (int r = 0; r < 4; r++) {
        int qi = q0w + 4 * g + r;
        if (qi > 512) continue;
        float rl = 1.0f / l[r];
        #pragma unroll
        for (int df = 0; df < 4; df++)
            out[(size_t)(b * 513 + qi) * 384 + h * 64 + df * 16 + l15] = (f16)(O[df][r] * rl);
    }
}

// ---------------- head: LN + MLP(384->384 gelu ->2) + sigmoid, 384 threads ----------------
__global__ __launch_bounds__(384) void head_kernel(
    const float* __restrict__ x, const float* __restrict__ lg, const float* __restrict__ lb,
    const float* __restrict__ w1, const float* __restrict__ b1,
    const float* __restrict__ w2, const float* __restrict__ b2,
    float* __restrict__ out)
{
    int b = blockIdx.x; int t = threadIdx.x;
    __shared__ float hs[384], h1[384];
    __shared__ float rs[6], rs2[6];
    const float* xp = x + (size_t)b * 513 * 384;
    float v = xp[t];
    float s = v, s2 = v * v;
    #pragma unroll
    for (int off = 32; off >= 1; off >>= 1) {
        s += __shfl_down(s, off); s2 += __shfl_down(s2, off);
    }
    if ((t & 63) == 0) { rs[t >> 6] = s; rs2[t >> 6] = s2; }
    __syncthreads();
    float S = 0.f, S2 = 0.f;
    #pragma unroll
    for (int i = 0; i < 6; i++) { S += rs[i]; S2 += rs2[i]; }
    float mu = S * (1.f / 384.f);
    float var = S2 * (1.f / 384.f) - mu * mu;
    float rstd = rsqrtf(var + EPSV);
    hs[t] = (v - mu) * rstd * lg[t] + lb[t];
    __syncthreads();
    const float* wr = w1 + (size_t)t * 384;
    float acc = b1[t];
    for (int c = 0; c < 384; c += 4) {
        float4 w4 = *reinterpret_cast<const float4*>(wr + c);
        acc += w4.x * hs[c] + w4.y * hs[c + 1] + w4.z * hs[c + 2] + w4.w * hs[c + 3];
    }
    h1[t] = gelu_f(acc);
    __syncthreads();
    float p0 = h1[t] * w2[t], p1 = h1[t] * w2[384 + t];
    #pragma unroll
    for (int off = 32; off >= 1; off >>= 1) {
        p0 += __shfl_down(p0, off); p1 += __shfl_down(p1, off);
    }
    if ((t & 63) == 0) { rs[t >> 6] = p0; rs2[t >> 6] = p1; }
    __syncthreads();
    if (t == 0) {
        float a0 = b2[0], a1 = b2[1];
        #pragma unroll
        for (int i = 0; i < 6; i++) { a0 += rs[i]; a1 += rs2[i]; }
        out[b * 2 + 0] = 1.f / (1.f + expf(-a0));
        out[b * 2 + 1] = 1.f / (1.f + expf(-a1));
    }
}

static inline int cdiv(int a, int b) { return (a + b - 1) / b; }

extern "C" void kernel_launch(void* const* d_in, const int* in_sizes, int n_in,
                              void* d_out, int out_size, void* d_ws, size_t ws_size,
                              hipStream_t stream)
{
    const float* frames  = (const float*)d_in[0];
    const float* conv1_w = (const float*)d_in[1];
    const float* bn1_g = (const float*)d_in[2]; const float* bn1_b = (const float*)d_in[3];
    const float* bn1_m = (const float*)d_in[4]; const float* bn1_v = (const float*)d_in[5];
    const float* conv2_w = (const float*)d_in[6];
    const float* bn2_g = (const float*)d_in[7]; const float* bn2_b = (const float*)d_in[8];
    const float* bn2_m = (const float*)d_in[9]; const float* bn2_v = (const float*)d_in[10];
    const float* conv3_w = (const float*)d_in[11];
    const float* bn3_g = (const float*)d_in[12]; const float* bn3_b = (const float*)d_in[13];
    const float* bn3_m = (const float*)d_in[14]; const float* bn3_v = (const float*)d_in[15];
    const float* proj_w = (const float*)d_in[16];
    const float* dw_w = (const float*)d_in[17]; const float* dw_b = (const float*)d_in[18];
    const float* pw_w = (const float*)d_in[19]; const float* pw_b = (const float*)d_in[20];
    const float* tnorm_g = (const float*)d_in[21]; const float* tnorm_b = (const float*)d_in[22];
    const float* frame_pos = (const float*)d_in[23];
    const float* patch_pos = (const float*)d_in[24];
    const float* cls_token = (const float*)d_in[25];
    const float* cls_pos = (const float*)d_in[26];
    const float* qkv_w = (const float*)d_in[27]; const float* qkv_b = (const float*)d_in[28];
    const float* out_w = (const float*)d_in[29]; const float* out_b = (const float*)d_in[30];
    const float* ln1_g = (const float*)d_in[31]; const float* ln1_b = (const float*)d_in[32];
    const float* ln2_g = (const float*)d_in[33]; const float* ln2_b = (const float*)d_in[34];
    const float* ffn_w1 = (const float*)d_in[35]; const float* ffn_b1 = (const float*)d_in[36];
    const float* ffn_w2 = (const float*)d_in[37]; const float* ffn_b2 = (const float*)d_in[38];
    const float* head_ln_g = (const float*)d_in[39]; const float* head_ln_b = (const float*)d_in[40];
    const float* head_w1 = (const float*)d_in[41]; const float* head_b1 = (const float*)d_in[42];
    const float* head_w2 = (const float*)d_in[43]; const float* head_b2 = (const float*)d_in[44];
    (void)in_sizes; (void)n_in; (void)out_size; (void)ws_size;

    char* base = (char*)d_ws;
    size_t off = 0;
    auto alloc = [&](size_t bytes) { void* p = base + off; off = (off + bytes + 255) & ~(size_t)255; return p; };

    // contiguous f16 weight block (order: proj, pw, qkv, out, ffn1, ffn2)
    f16* wtotal = (f16*)alloc((size_t)10960896 * 2);
    f16* projw16 = wtotal;
    f16* pw16    = wtotal + 49152;
    f16* qkvw16  = wtotal + 344064;
    f16* outw16  = wtotal + 2998272;
    f16* f1w16   = wtotal + 3883008;
    f16* f2w16   = wtotal + 7421952;
    f16* c2w16   = (f16*)alloc((size_t)64 * 288 * 2);
    f16* c3w16   = (f16*)alloc((size_t)128 * 576 * 2);
    // activations
    float* tokens = (float*)alloc((size_t)4096 * 384 * 4);
    f16* pooled   = (f16*)alloc((size_t)4096 * 128 * 2);
    f16* c1h = (f16*)alloc((size_t)64 * 64 * 64 * 32 * 2);
    f16* c2h = (f16*)alloc((size_t)64 * 32 * 32 * 64 * 2);
    f16* c3h = (f16*)alloc((size_t)64 * 16 * 16 * 128 * 2);
    float* tc = (float*)alloc((size_t)4096 * 384 * 4);
    float* mA = (float*)alloc((size_t)4096 * 384 * 4);
    float* mB = (float*)alloc((size_t)4096 * 384 * 4);
    f16*   mh = (f16*)alloc((size_t)4096 * 384 * 2);
    float* xb   = (float*)alloc((size_t)8 * 513 * 384 * 4);
    f16*   hb   = (f16*)alloc((size_t)8 * 513 * 384 * 2);
    f16*   qkvb = (f16*)alloc((size_t)8 * 513 * 1152 * 2);
    f16*   vTb  = (f16*)alloc((size_t)48 * 64 * 576 * 2);
    f16*   ob   = (f16*)alloc((size_t)8 * 513 * 384 * 2);
    f16*   ffb  = (f16*)alloc((size_t)8 * 513 * 1536 * 2);

    // ---------- weight conversion (one dispatch) + conv reorders ----------
    cvt_all_kernel<<<4096, 256, 0, stream>>>(
        proj_w, pw_w, qkv_w, out_w, ffn_w1, ffn_w2, wtotal);
    conv_w_reorder_kernel<<<cdiv(64 * 288, 256), 256, 0, stream>>>(conv2_w, c2w16, 64, 32);
    conv_w_reorder_kernel<<<cdiv(128 * 576, 256), 256, 0, stream>>>(conv3_w, c3w16, 128, 64);

    // ---------- conv stem, 4 chunks of 64 frames ----------
    for (int ch = 0; ch < 4; ch++) {
        const float* fch = frames + (size_t)ch * 64 * 16384;
        conv1_wave_kernel<<<64 * 16, 256, 0, stream>>>(
            fch, conv1_w, bn1_g, bn1_b, bn1_m, bn1_v, c1h);
        convg_kernel<32, 64, 64><<<dim3(1024, 1), 256, 0, stream>>>(
            c1h, c2w16, bn2_g, bn2_b, bn2_m, bn2_v, c2h);
        convg_kernel<64, 32, 128><<<dim3(256, 2), 256, 0, stream>>>(
            c2h, c3w16, bn3_g, bn3_b, bn3_m, bn3_v, c3h);
        poolh_kernel<<<64, 256, 0, stream>>>(c3h, pooled + (size_t)ch * 1024 * 128, 64);
    }
    gemm_h_kernel<0, 0, 0><<<dim3(6, 64), 256, 0, stream>>>(
        pooled, projw16, nullptr, nullptr, tokens, nullptr, 4096, 384, 128);

    // ---------- temporal mixer ----------
    tok2tc_kernel<<<cdiv(8 * 32 * 16 * 384, 256), 256, 0, stream>>>(tokens, tc);
    hipMemcpyAsync(mA, tc, (size_t)4096 * 384 * sizeof(float), hipMemcpyDeviceToDevice, stream);
    float* cur = mA; float* alt = mB;
    for (int it = 0; it < 2; it++) {
        int dil = (it == 0) ? 1 : 2;
        dwconv_kernel<<<cdiv(128 * 32 * 384, 256), 256, 0, stream>>>(
            cur, dw_w + (size_t)it * 384 * 3, dw_b + (size_t)it * 384, mh, dil);
        gemm_h_kernel<0, 0, 0><<<dim3(6, 64), 256, 0, stream>>>(
            mh, pw16 + (size_t)it * 384 * 384, pw_b + (size_t)it * 384, cur,
            alt, nullptr, 4096, 384, 384);
        float* tmp = cur; cur = alt; alt = tmp;
    }

    // ---------- build transformer input x ----------
    build_x_kernel<<<128 * 32, 128, 0, stream>>>(
        cur, tc, tnorm_g, tnorm_b, frame_pos, patch_pos, xb);
    cls_kernel<<<cdiv(8 * 384, 256), 256, 0, stream>>>(cls_token, cls_pos, xb);

    // ---------- transformer ----------
    const int M = 8 * 513;   // 4104
    const int MG = cdiv(M, 64);   // 65
    for (int l = 0; l < 6; l++) {
        ln_kernel<<<M, 128, 0, stream>>>(xb,
            ln1_g + (size_t)l * 384, ln1_b + (size_t)l * 384, hb, M);
        gemm_h_kernel<1, 0, 1><<<dim3(18, MG), 256, 0, stream>>>(
            hb, qkvw16 + (size_t)l * 1152 * 384, qkv_b + (size_t)l * 1152,
            nullptr, qkvb, vTb, M, 1152, 384);
        fattn_h_kernel<<<dim3(9, 48), 256, 0, stream>>>(qkvb, vTb, ob);
        gemm_h_kernel<0, 0, 0><<<dim3(6, MG), 256, 0, stream>>>(
            ob, outw16 + (size_t)l * 384 * 384, out_b + (size_t)l * 384,
            xb, xb, nullptr, M, 384, 384);
        ln_kernel<<<M, 128, 0, stream>>>(xb,
            ln2_g + (size_t)l * 384, ln2_b + (size_t)l * 384, hb, M);
        gemm_h_kernel<1, 1, 0><<<dim3(24, MG), 256, 0, stream>>>(
            hb, f1w16 + (size_t)l * 1536 * 384, ffn_b1 + (size_t)l * 1536,
            nullptr, ffb, nullptr, M, 1536, 384);
        gemm_h_kernel<0, 0, 0><<<dim3(6, MG), 256, 0, stream>>>(
            ffb, f2w16 + (size_t)l * 384 * 1536, ffn_b2 + (size_t)l * 384,
            xb, xb, nullptr, M, 384, 1536);
    }

    // ---------- head ----------
    head_kernel<<<8, 384, 0, stream>>>(
        xb, head_ln_g, head_ln_b, head_w1, head_b1, head_w2, head_b2, (float*)d_out);
}